// Round 3
// baseline (4677.388 us; speedup 1.0000x reference)
//
#include <hip/hip_runtime.h>

typedef unsigned short u16;
typedef __attribute__((ext_vector_type(8))) short short8;
typedef __attribute__((ext_vector_type(4))) float floatx4;

__device__ __forceinline__ float bf2f(u16 u) {
    union { unsigned int i; float f; } v; v.i = ((unsigned int)u) << 16; return v.f;
}
__device__ __forceinline__ u16 f2bf(float f) {
    union { float f; unsigned int i; } v; v.f = f;
    unsigned int i = v.i + 0x7fffu + ((v.i >> 16) & 1u);  // RNE
    return (u16)(i >> 16);
}

// ---------------- dtype sniffer: flag=1 means inputs are float32 ----------------
__global__ __launch_bounds__(256) void sniff_k(const u16* __restrict__ x, int* __restrict__ flag) {
    __shared__ int red[4];
    int cnt = 0;
    for (int i = 0; i < 16; ++i) {
        u16 v = x[(threadIdx.x * 16 + i) * 2];
        int e = (v >> 7) & 0xFF;
        if (e >= 110 && e <= 135) cnt++;
    }
    #pragma unroll
    for (int off = 32; off; off >>= 1) cnt += __shfl_down(cnt, off);
    if ((threadIdx.x & 63) == 0) red[threadIdx.x >> 6] = cnt;
    __syncthreads();
    if (threadIdx.x == 0) {
        int tot = red[0] + red[1] + red[2] + red[3];
        *flag = (tot < 2048) ? 1 : 0;
    }
}

__device__ __forceinline__ float ldin(const void* p, size_t i, int isf32) {
    return isf32 ? ((const float*)p)[i] : bf2f(((const u16*)p)[i]);
}

// ---------------- canonicalize param to f32 ----------------
__global__ __launch_bounds__(256) void cvt2_k(const void* __restrict__ in, float* __restrict__ out,
                                              int n, const int* __restrict__ flag) {
    int isf32 = *flag;
    int i = blockIdx.x * 256 + threadIdx.x;
    if (i < n) out[i] = ldin(in, i, isf32);
}

// ---------------- guard diagnostic fill ----------------
__global__ __launch_bounds__(256) void fill_k(float* __restrict__ p, int n) {
    int i = blockIdx.x * 256 + threadIdx.x;
    if (i < n) p[i] = 1.0e6f;
}

// ---------------- conv stem: 1->32, k3 s2 p1 ----------------
__global__ __launch_bounds__(256) void conv1_k(const void* __restrict__ x, const float* __restrict__ w,
                                               const float* __restrict__ bias, float* __restrict__ out,
                                               const int* __restrict__ flag) {
    int isf32 = *flag;
    int idx = blockIdx.x * 256 + threadIdx.x;
    int t  = idx & 511;
    int f  = (idx >> 9) & 63;
    int co = (idx >> 15) & 31;
    int b  = idx >> 20;
    size_t xb = (size_t)b * 128 * 1024;
    float acc = bias[co];
    #pragma unroll
    for (int df = 0; df < 3; ++df) {
        int fi = 2 * f + df - 1;
        if (fi < 0 || fi >= 128) continue;
        #pragma unroll
        for (int dt = 0; dt < 3; ++dt) {
            int ti = 2 * t + dt - 1;
            if (ti < 0 || ti >= 1024) continue;
            acc += w[co * 9 + df * 3 + dt] * ldin(x, xb + (size_t)fi * 1024 + ti, isf32);
        }
    }
    out[idx] = acc;
}

// ---------------- LN-over-f stats ----------------
__global__ __launch_bounds__(256) void stats_k(const float* __restrict__ X, float* __restrict__ sm,
                                               float* __restrict__ sr) {
    int idx = blockIdx.x * 256 + threadIdx.x;  // 16*32*512
    int t  = idx & 511;
    int bc = idx >> 9;
    const float* p = X + (size_t)bc * 64 * 512 + t;
    float s = 0.f, s2 = 0.f;
    #pragma unroll 8
    for (int f = 0; f < 64; ++f) { float v = p[f * 512]; s += v; s2 += v * v; }
    float m  = s * (1.f / 64.f);
    float var = fmaxf(s2 * (1.f / 64.f) - m * m, 0.f);
    sm[idx] = m;
    sr[idx] = rsqrtf(var + 1e-5f);
}

// ---------------- fused LN+ReLU+conv 32->32 k3 s1 p1 (+opt residual) ----------------
__global__ __launch_bounds__(256) void convf_k(const float* in, float* out,
                                               const float* sm, const float* sr,
                                               const float* g, const float* be,
                                               const float* w, const float* bias,
                                               const float* res) {
    __shared__ float tile[32][10][34];
    int t0 = blockIdx.x * 32;
    int f0 = blockIdx.y * 8;
    int b  = blockIdx.z;
    const float* inb = in + (size_t)b * 32 * 64 * 512;
    for (int i = threadIdx.x; i < 32 * 10 * 34; i += 256) {
        int ci  = i / 340;
        int rem = i % 340;
        int fr  = rem / 34;
        int tc  = rem % 34;
        int gf = f0 + fr - 1, gt = t0 + tc - 1;
        float v = 0.f;
        if (gf >= 0 && gf < 64 && gt >= 0 && gt < 512) {
            float xv = inb[((size_t)ci * 64 + gf) * 512 + gt];
            int si = (b * 32 + ci) * 512 + gt;
            v = fmaxf((xv - sm[si]) * sr[si] * g[gf] + be[gf], 0.f);
        }
        tile[ci][fr][tc] = v;
    }
    __syncthreads();
    int fl = threadIdx.x >> 5;
    int tl = threadIdx.x & 31;
    float acc[32];
    #pragma unroll
    for (int co = 0; co < 32; ++co) acc[co] = 0.f;
    for (int ci = 0; ci < 32; ++ci) {
        float xv[9];
        #pragma unroll
        for (int df = 0; df < 3; ++df)
            #pragma unroll
            for (int dt = 0; dt < 3; ++dt)
                xv[df * 3 + dt] = tile[ci][fl + df][tl + dt];
        const float* wp = w + ci * 9;  // [co][ci][3][3]
        #pragma unroll
        for (int co = 0; co < 32; ++co) {
            const float* wc = wp + co * 288;
            float a = acc[co];
            #pragma unroll
            for (int k = 0; k < 9; ++k) a = fmaf(wc[k], xv[k], a);
            acc[co] = a;
        }
    }
    int f = f0 + fl, t = t0 + tl;
    #pragma unroll
    for (int co = 0; co < 32; ++co) {
        size_t oi = (((size_t)b * 32 + co) * 64 + f) * 512 + t;
        float v = acc[co] + bias[co];
        if (res) v += res[oi];
        out[oi] = v;
    }
}

// ---------------- transpose (b,c,f,t) f32 -> A[(t*16+b)][(c*64+f)] bf16 ----------------
__global__ __launch_bounds__(256) void transpose_k(const float* __restrict__ X, u16* __restrict__ A) {
    __shared__ float tile[64][65];
    int t0 = blockIdx.x * 64;
    int c  = blockIdx.y;
    int b  = blockIdx.z;
    const float* p = X + (((size_t)b * 32 + c) * 64) * 512 + t0;
    #pragma unroll
    for (int i = 0; i < 16; ++i) {
        int f = i * 4 + (threadIdx.x >> 6);
        int t = threadIdx.x & 63;
        tile[f][t] = p[(size_t)f * 512 + t];
    }
    __syncthreads();
    #pragma unroll
    for (int i = 0; i < 16; ++i) {
        int t = i * 4 + (threadIdx.x >> 6);
        int f = threadIdx.x & 63;
        A[((size_t)(t0 + t) * 16 + b) * 2048 + c * 64 + f] = f2bf(tile[f][t]);
    }
}

// ---------------- row layernorm, f32 in -> bf16 out ----------------
__global__ __launch_bounds__(256) void lnlast_k(const float* __restrict__ X, u16* __restrict__ Y,
                                                const float* __restrict__ g, const float* __restrict__ bt,
                                                int width) {
    int row = blockIdx.x;
    const float* p = X + (size_t)row * width;
    float s = 0.f, s2 = 0.f;
    for (int i = threadIdx.x; i < width; i += 256) { float v = p[i]; s += v; s2 += v * v; }
    #pragma unroll
    for (int off = 32; off; off >>= 1) { s += __shfl_down(s, off); s2 += __shfl_down(s2, off); }
    __shared__ float red[4][2];
    int wv = threadIdx.x >> 6;
    if ((threadIdx.x & 63) == 0) { red[wv][0] = s; red[wv][1] = s2; }
    __syncthreads();
    if (threadIdx.x == 0) {
        float a = 0.f, b2 = 0.f;
        for (int i = 0; i < 4; ++i) { a += red[i][0]; b2 += red[i][1]; }
        float m = a / width;
        float var = fmaxf(b2 / width - m * m, 0.f);
        red[0][0] = m; red[0][1] = rsqrtf(var + 1e-5f);
    }
    __syncthreads();
    float m = red[0][0], rs = red[0][1];
    u16* q = Y + (size_t)row * width;
    for (int i = threadIdx.x; i < width; i += 256)
        q[i] = f2bf((p[i] - m) * rs * g[i] + bt[i]);
}

// ---------------- MFMA bf16 GEMM: C = A@B (+bias, relu). B dual-dtype, bofs in elements ----
__global__ __launch_bounds__(256) void gemm_k(const u16* __restrict__ A, int lda,
                                              const void* __restrict__ B, int ldb, int bofs,
                                              float* __restrict__ C, int ldc,
                                              const float* __restrict__ bias, int relu, int K,
                                              const int* __restrict__ flag) {
    int isf32 = *flag;
    __shared__ u16 As[64 * 32];  // [m][k]
    __shared__ u16 Bs[64 * 32];  // [n][k]
    int tid  = threadIdx.x;
    int bm   = blockIdx.x * 64;
    int bn   = blockIdx.y * 64;
    int wave = tid >> 6;
    int lane = tid & 63;
    int quad = lane >> 4;
    int r    = lane & 15;
    int wm   = (wave >> 1) * 32;
    int wn   = (wave & 1) * 32;
    floatx4 acc[2][2];
    #pragma unroll
    for (int i = 0; i < 2; ++i)
        #pragma unroll
        for (int j = 0; j < 2; ++j)
            #pragma unroll
            for (int k = 0; k < 4; ++k) acc[i][j][k] = 0.f;

    int arow = tid >> 2, aseg = (tid & 3) * 8;
    int brow = tid >> 3, bseg = (tid & 7) * 8;

    for (int k0 = 0; k0 < K; k0 += 32) {
        uint4 av = *(const uint4*)(A + (size_t)(bm + arow) * lda + k0 + aseg);
        *(uint4*)(As + arow * 32 + aseg) = av;
        size_t boff = (size_t)(k0 + brow) * ldb + bofs + bn + bseg;
        if (isf32) {
            const float* Bf = (const float*)B;
            float4 v0 = *(const float4*)(Bf + boff);
            float4 v1 = *(const float4*)(Bf + boff + 4);
            Bs[(bseg + 0) * 32 + brow] = f2bf(v0.x);
            Bs[(bseg + 1) * 32 + brow] = f2bf(v0.y);
            Bs[(bseg + 2) * 32 + brow] = f2bf(v0.z);
            Bs[(bseg + 3) * 32 + brow] = f2bf(v0.w);
            Bs[(bseg + 4) * 32 + brow] = f2bf(v1.x);
            Bs[(bseg + 5) * 32 + brow] = f2bf(v1.y);
            Bs[(bseg + 6) * 32 + brow] = f2bf(v1.z);
            Bs[(bseg + 7) * 32 + brow] = f2bf(v1.w);
        } else {
            const u16* Bh = (const u16*)B;
            union { uint4 v; u16 e[8]; } bb;
            bb.v = *(const uint4*)(Bh + boff);
            #pragma unroll
            for (int j = 0; j < 8; ++j) Bs[(bseg + j) * 32 + brow] = bb.e[j];
        }
        __syncthreads();
        short8 af[2], bf[2];
        #pragma unroll
        for (int mi = 0; mi < 2; ++mi) af[mi] = *(const short8*)(As + (wm + mi * 16 + r) * 32 + quad * 8);
        #pragma unroll
        for (int ni = 0; ni < 2; ++ni) bf[ni] = *(const short8*)(Bs + (wn + ni * 16 + r) * 32 + quad * 8);
        #pragma unroll
        for (int mi = 0; mi < 2; ++mi)
            #pragma unroll
            for (int ni = 0; ni < 2; ++ni)
                acc[mi][ni] = __builtin_amdgcn_mfma_f32_16x16x32_bf16(af[mi], bf[ni], acc[mi][ni], 0, 0, 0);
        __syncthreads();
    }
    // C/D layout: col = lane&15, row = quad*4 + reg
    #pragma unroll
    for (int mi = 0; mi < 2; ++mi)
        #pragma unroll
        for (int ni = 0; ni < 2; ++ni) {
            int col = bn + wn + ni * 16 + r;
            #pragma unroll
            for (int reg = 0; reg < 4; ++reg) {
                int row = bm + wm + mi * 16 + quad * 4 + reg;
                float v = acc[mi][ni][reg];
                if (bias) v += bias[col];
                if (relu) v = fmaxf(v, 0.f);
                C[(size_t)row * ldc + col] = v;
            }
        }
}

// ---------------- SRU recurrence, one 256-step chunk, both dirs ----------------
#define TC 256
__global__ __launch_bounds__(256) void scan_k(const float* __restrict__ Uf, const float* __restrict__ Ub,
                                              const float* __restrict__ Xp, float* __restrict__ Xn,
                                              float* __restrict__ cstate, const float* __restrict__ vv,
                                              const float* __restrict__ bb, int t0f, int t0b, int init) {
    int gid = blockIdx.x * 256 + threadIdx.x;  // 16384
    int d  = gid >> 13;
    int b  = (gid >> 9) & 15;
    int h  = gid & 511;
    float v0 = vv[(d * 2 + 0) * 512 + h];
    float v1 = vv[(d * 2 + 1) * 512 + h];
    float b0 = bb[(d * 2 + 0) * 512 + h];
    float b1 = bb[(d * 2 + 1) * 512 + h];
    const float* u  = (d ? Ub : Uf) + (size_t)b * 1536 + h;
    int t0 = d ? t0b : t0f;
    const float* xb = Xp + (size_t)b * 1024 + d * 512 + h;
    float*       ob = Xn + (size_t)b * 1024 + d * 512 + h;
    float c = init ? 0.f : cstate[gid];
    for (int s = 0; s < TC; ++s) {
        int sl = d ? (TC - 1 - s) : s;
        size_t ro = (size_t)sl * 16 * 1536;
        size_t xo = (size_t)(t0 + sl) * 16 * 1024;
        float u0 = u[ro];
        float fp = u[ro + 512]  + b0;
        float rp = u[ro + 1024] + b1;
        float xr = xb[xo];
        float f = 1.f / (1.f + __expf(-(fp + v0 * c)));
        float r = 1.f / (1.f + __expf(-(rp + v1 * c)));
        c = f * c + (1.f - f) * u0;
        float th = 1.f - 2.f / (__expf(2.f * c) + 1.f);  // tanh(c)
        ob[xo] = r * th + (1.f - r) * xr;
    }
    cstate[gid] = c;
}

// ---------------- classifier head ----------------
__global__ __launch_bounds__(256) void cls2_k(const float* __restrict__ FC1, const float* __restrict__ W2,
                                              const float* __restrict__ b2, void* __restrict__ out,
                                              const int* __restrict__ flag) {
    int isf32 = *flag;
    int row = blockIdx.x * 4 + (threadIdx.x >> 6);
    int v   = threadIdx.x & 63;
    if (v >= 29) return;
    const float* p = FC1 + (size_t)row * 512;
    float acc = 0.f;
    for (int k = 0; k < 512; ++k) acc = fmaf(p[k], W2[k * 29 + v], acc);
    acc += b2[v];
    int t = row >> 4, b = row & 15;
    size_t oi = ((size_t)b * 512 + t) * 29 + v;
    if (isf32) ((float*)out)[oi] = acc;
    else       ((u16*)out)[oi]   = f2bf(acc);
}

// ---------------- launch ----------------
extern "C" void kernel_launch(void* const* d_in, const int* in_sizes, int n_in,
                              void* d_out, int out_size, void* d_ws, size_t ws_size,
                              hipStream_t stream) {
    const void* x        = d_in[0];
    const void* cnn_w    = d_in[1];
    const void* cnn_b    = d_in[2];
    const void* res_w1   = d_in[3];
    const void* res_b1   = d_in[4];
    const void* res_w2   = d_in[5];
    const void* res_b2   = d_in[6];
    const void* ln1_g    = d_in[7];
    const void* ln1_b    = d_in[8];
    const void* ln2_g    = d_in[9];
    const void* ln2_b    = d_in[10];
    const void* proj_w   = d_in[11];
    const void* sru_w    = d_in[12];
    const void* sru_v    = d_in[13];
    const void* sru_b    = d_in[14];
    const void* sru_ln_g = d_in[15];
    const void* sru_ln_b = d_in[16];
    const void* cls_ln_g = d_in[17];
    const void* cls_ln_b = d_in[18];
    const void* cls_w1   = d_in[19];
    const void* cls_b1   = d_in[20];
    const void* cls_w2   = d_in[21];
    const void* cls_b2   = d_in[22];

    float* ws = (float*)d_ws;
    const size_t O_X    = 0;
    const size_t O_C    = 16777216;
    const size_t O_ST_M = 33554432;
    const size_t O_ST_R = 33816576;
    const size_t O_CST  = 34078720;
    const size_t O_PARK = 34095104;
    const size_t O_FLAG = 34187552;
    const size_t TOTAL  = 34187568;   // 130.4 MiB
    if (ws_size < TOTAL * sizeof(float)) {
        fill_k<<<(out_size + 255) / 256, 256, 0, stream>>>((float*)d_out, out_size);
        return;  // diagnostic: absmax ~1e6 => ws too small
    }

    u16*   Abf = (u16*)(ws + O_C);
    float* XP0 = ws + 25165824;
    u16*   XL  = (u16*)(ws + 0);
    float* XP1 = ws + 4194304;
    float* Uf  = ws + 12582912;
    float* Ub  = ws + 18874368;
    float* FC1 = ws + 12582912;
    float* X   = ws + O_X;
    float* C   = ws + O_C;
    float* SM  = ws + O_ST_M;
    float* SR  = ws + O_ST_R;
    float* CST = ws + O_CST;
    float* PK  = ws + O_PARK;
    int*   FLG = (int*)(ws + O_FLAG);

    float* p_cnn_w = PK + 0;      float* p_cnn_b = PK + 288;
    float* p_rw1   = PK + 320;    float* p_rb1   = PK + 27968;
    float* p_rw2   = PK + 28064;  float* p_rb2   = PK + 55712;
    float* p_l1g   = PK + 55808;  float* p_l1b   = PK + 56000;
    float* p_l2g   = PK + 56192;  float* p_l2b   = PK + 56384;
    float* p_sv    = PK + 56576;  float* p_sb    = PK + 62720;
    float* p_slng  = PK + 68864;  float* p_slnb  = PK + 71936;
    float* p_clng  = PK + 75008;  float* p_clnb  = PK + 76032;
    float* p_cb1   = PK + 77056;  float* p_cw2   = PK + 77568;
    float* p_cb2   = PK + 92416;

    sniff_k<<<1, 256, 0, stream>>>((const u16*)x, FLG);

    #define CVT(src, dst, n) cvt2_k<<<((n) + 255) / 256, 256, 0, stream>>>(src, dst, n, FLG)
    CVT(cnn_w,  p_cnn_w, 288);   CVT(cnn_b, p_cnn_b, 32);
    CVT(res_w1, p_rw1, 27648);   CVT(res_b1, p_rb1, 96);
    CVT(res_w2, p_rw2, 27648);   CVT(res_b2, p_rb2, 96);
    CVT(ln1_g,  p_l1g, 192);     CVT(ln1_b, p_l1b, 192);
    CVT(ln2_g,  p_l2g, 192);     CVT(ln2_b, p_l2b, 192);
    CVT(sru_v,  p_sv, 6144);     CVT(sru_b, p_sb, 6144);
    CVT(sru_ln_g, p_slng, 3072); CVT(sru_ln_b, p_slnb, 3072);
    CVT(cls_ln_g, p_clng, 1024); CVT(cls_ln_b, p_clnb, 1024);
    CVT(cls_b1, p_cb1, 512);     CVT(cls_w2, p_cw2, 14848);
    CVT(cls_b2, p_cb2, 29);
    #undef CVT

    conv1_k<<<65536, 256, 0, stream>>>(x, p_cnn_w, p_cnn_b, X, FLG);

    for (int i = 0; i < 3; ++i) {
        stats_k<<<1024, 256, 0, stream>>>(X, SM, SR);
        convf_k<<<dim3(16, 8, 16), 256, 0, stream>>>(X, C, SM, SR, p_l1g + i * 64, p_l1b + i * 64,
                                                     p_rw1 + i * 9216, p_rb1 + i * 32, nullptr);
        stats_k<<<1024, 256, 0, stream>>>(C, SM, SR);
        convf_k<<<dim3(16, 8, 16), 256, 0, stream>>>(C, X, SM, SR, p_l2g + i * 64, p_l2b + i * 64,
                                                     p_rw2 + i * 9216, p_rb2 + i * 32, X);
    }

    transpose_k<<<dim3(8, 32, 16), 256, 0, stream>>>(X, Abf);
    gemm_k<<<dim3(128, 16), 256, 0, stream>>>(Abf, 2048, proj_w, 1024, 0, XP0, 1024, nullptr, 0, 2048, FLG);

    float* cur = XP0;
    float* nxt = XP1;
    for (int l = 0; l < 3; ++l) {
        lnlast_k<<<8192, 256, 0, stream>>>(cur, XL, p_slng + l * 1024, p_slnb + l * 1024, 1024);
        const char* wl = (const char*)sru_w;  // element offset handled via bofs
        size_t lofs = (size_t)l * 3145728;    // elements into sru_w for this layer
        for (int j = 0; j < 2; ++j) {
            int t0f = j * TC;
            int t0b = (1 - j) * TC;
            gemm_k<<<dim3(64, 24), 256, 0, stream>>>(XL + (size_t)t0f * 16 * 1024, 1024,
                                                     sru_w, 3072, (int)lofs, Uf, 1536, nullptr, 0, 1024, FLG);
            gemm_k<<<dim3(64, 24), 256, 0, stream>>>(XL + (size_t)t0b * 16 * 1024, 1024,
                                                     sru_w, 3072, (int)lofs + 1536, Ub, 1536, nullptr, 0, 1024, FLG);
            scan_k<<<64, 256, 0, stream>>>(Uf, Ub, cur, nxt, CST,
                                           p_sv + l * 2048, p_sb + l * 2048, t0f, t0b, j == 0);
        }
        float* tmp = cur; cur = nxt; nxt = tmp;
        (void)wl;
    }

    lnlast_k<<<8192, 256, 0, stream>>>(cur, XL, p_clng, p_clnb, 1024);
    gemm_k<<<dim3(128, 8), 256, 0, stream>>>(XL, 1024, cls_w1, 512, 0, FC1, 512, p_cb1, 1, 1024, FLG);
    cls2_k<<<2048, 256, 0, stream>>>(FC1, p_cw2, p_cb2, d_out, FLG);
}

// Round 4
// 2760.844 us; speedup vs baseline: 1.6942x; 1.6942x over previous
//
#include <hip/hip_runtime.h>

typedef unsigned short u16;
typedef __attribute__((ext_vector_type(8))) short short8;
typedef __attribute__((ext_vector_type(4))) float floatx4;

__device__ __forceinline__ float bf2f(u16 u) {
    union { unsigned int i; float f; } v; v.i = ((unsigned int)u) << 16; return v.f;
}
__device__ __forceinline__ u16 f2bf(float f) {
    union { float f; unsigned int i; } v; v.f = f;
    unsigned int i = v.i + 0x7fffu + ((v.i >> 16) & 1u);  // RNE
    return (u16)(i >> 16);
}

// ---------------- dtype sniffer: flag=1 means inputs are float32 ----------------
__global__ __launch_bounds__(256) void sniff_k(const u16* __restrict__ x, int* __restrict__ flag) {
    __shared__ int red[4];
    int cnt = 0;
    for (int i = 0; i < 16; ++i) {
        u16 v = x[(threadIdx.x * 16 + i) * 2];
        int e = (v >> 7) & 0xFF;
        if (e >= 110 && e <= 135) cnt++;
    }
    #pragma unroll
    for (int off = 32; off; off >>= 1) cnt += __shfl_down(cnt, off);
    if ((threadIdx.x & 63) == 0) red[threadIdx.x >> 6] = cnt;
    __syncthreads();
    if (threadIdx.x == 0) {
        int tot = red[0] + red[1] + red[2] + red[3];
        *flag = (tot < 2048) ? 1 : 0;
    }
}

__device__ __forceinline__ float ldin(const void* p, size_t i, int isf32) {
    return isf32 ? ((const float*)p)[i] : bf2f(((const u16*)p)[i]);
}

// ---------------- canonicalize all params to f32 park (one launch) ----------------
struct CvtArgs {
    const void* src[19];
    int len[19];
    int off[19];
};
__global__ __launch_bounds__(256) void cvtall_k(CvtArgs a, float* __restrict__ dst,
                                                const int* __restrict__ flag) {
    int isf32 = *flag;
    int seg = blockIdx.y;
    int n = a.len[seg];
    const void* s = a.src[seg];
    float* d = dst + a.off[seg];
    for (int i = blockIdx.x * 256 + threadIdx.x; i < n; i += gridDim.x * 256)
        d[i] = ldin(s, i, isf32);
}

// ---------------- guard diagnostic fill ----------------
__global__ __launch_bounds__(256) void fill_k(float* __restrict__ p, int n) {
    int i = blockIdx.x * 256 + threadIdx.x;
    if (i < n) p[i] = 1.0e6f;
}

// ---------------- conv stem: 1->32, k3 s2 p1 ----------------
__global__ __launch_bounds__(256) void conv1_k(const void* __restrict__ x, const float* __restrict__ w,
                                               const float* __restrict__ bias, float* __restrict__ out,
                                               const int* __restrict__ flag) {
    int isf32 = *flag;
    int idx = blockIdx.x * 256 + threadIdx.x;
    int t  = idx & 511;
    int f  = (idx >> 9) & 63;
    int co = (idx >> 15) & 31;
    int b  = idx >> 20;
    size_t xb = (size_t)b * 128 * 1024;
    float acc = bias[co];
    #pragma unroll
    for (int df = 0; df < 3; ++df) {
        int fi = 2 * f + df - 1;
        if (fi < 0 || fi >= 128) continue;
        #pragma unroll
        for (int dt = 0; dt < 3; ++dt) {
            int ti = 2 * t + dt - 1;
            if (ti < 0 || ti >= 1024) continue;
            acc += w[co * 9 + df * 3 + dt] * ldin(x, xb + (size_t)fi * 1024 + ti, isf32);
        }
    }
    out[idx] = acc;
}

// ---------------- LN-over-f stats ----------------
__global__ __launch_bounds__(256) void stats_k(const float* __restrict__ X, float* __restrict__ sm,
                                               float* __restrict__ sr) {
    int idx = blockIdx.x * 256 + threadIdx.x;  // 16*32*512
    int t  = idx & 511;
    int bc = idx >> 9;
    const float* p = X + (size_t)bc * 64 * 512 + t;
    float s = 0.f, s2 = 0.f;
    #pragma unroll 8
    for (int f = 0; f < 64; ++f) { float v = p[f * 512]; s += v; s2 += v * v; }
    float m  = s * (1.f / 64.f);
    float var = fmaxf(s2 * (1.f / 64.f) - m * m, 0.f);
    sm[idx] = m;
    sr[idx] = rsqrtf(var + 1e-5f);
}

// ---------------- fused LN+ReLU+conv32 via MFMA (implicit GEMM) ----------------
// grid (8 f-tiles, 8 t-tiles, 16 b), block 256 (4 waves).
// Block computes out[b][all 32 co][f0..f0+7][t0..t0+63]. Wave w: t sub-tile w*16.
// K = ci (32) per (df,dt); 9 positions -> 9 MFMA k-steps per output tile.
// LDS: act[f' 0..9][t' 0..65][ci 32] bf16, ci-octet XOR-swizzled by (t'&3).
__global__ __launch_bounds__(256) void convm_k(const float* __restrict__ in, float* __restrict__ out,
                                               const float* __restrict__ sm, const float* __restrict__ sr,
                                               const float* __restrict__ g, const float* __restrict__ be,
                                               const float* __restrict__ w, const float* __restrict__ bias,
                                               const float* __restrict__ res) {
    __shared__ u16 act[10 * 66 * 32];  // 42240 B
    int f0 = blockIdx.x * 8;
    int t0 = blockIdx.y * 64;
    int b  = blockIdx.z;
    const float* inb = in + (size_t)b * 32 * 64 * 512;

    int lane = threadIdx.x & 63;
    int wv   = threadIdx.x >> 6;
    int quad = lane >> 4;
    int r    = lane & 15;

    // B-fragments: B[k=ci][n=co], lane holds k=quad*8+j, n=r; co = ct*16+r
    short8 bfrag[3][3][2];
    #pragma unroll
    for (int df = 0; df < 3; ++df)
        #pragma unroll
        for (int dt = 0; dt < 3; ++dt)
            #pragma unroll
            for (int ct = 0; ct < 2; ++ct) {
                short8 v;
                #pragma unroll
                for (int j = 0; j < 8; ++j) {
                    int co = ct * 16 + r, ci = quad * 8 + j;
                    v[j] = (short)f2bf(w[(co * 32 + ci) * 9 + df * 3 + dt]);
                }
                bfrag[df][dt][ct] = v;
            }

    // stage LDS: 660 (f',t') pairs; global reads coalesced over t'
    for (int i = threadIdx.x; i < 660; i += 256) {
        int fp = i / 66;                 // f = f0 + fp - 1
        int tp = i % 66;                 // t = t0 + tp - 1
        int gf = f0 + fp - 1, gt = t0 + tp - 1;
        int sw = (tp & 3);               // octet swizzle
        u16* dstrow = &act[(fp * 66 + tp) * 32];
        if (gf < 0 || gf >= 64 || gt < 0 || gt >= 512) {
            #pragma unroll
            for (int o = 0; o < 4; ++o) {
                short8 z = {0,0,0,0,0,0,0,0};
                *(short8*)&dstrow[(o ^ sw) * 8] = z;
            }
        } else {
            float gg = g[gf], bb2 = be[gf];
            #pragma unroll
            for (int o = 0; o < 4; ++o) {
                short8 v;
                #pragma unroll
                for (int j = 0; j < 8; ++j) {
                    int ci = o * 8 + j;
                    float xv = inb[((size_t)ci * 64 + gf) * 512 + gt];
                    int si = (b * 32 + ci) * 512 + gt;
                    v[j] = (short)f2bf(fmaxf((xv - sm[si]) * sr[si] * gg + bb2, 0.f));
                }
                *(short8*)&dstrow[(o ^ sw) * 8] = v;
            }
        }
    }
    __syncthreads();

    floatx4 acc[8][2];
    #pragma unroll
    for (int i = 0; i < 8; ++i)
        #pragma unroll
        for (int j = 0; j < 2; ++j)
            #pragma unroll
            for (int k = 0; k < 4; ++k) acc[i][j][k] = 0.f;

    int tw = wv * 16;
    #pragma unroll
    for (int fh = 0; fh < 10; ++fh) {
        short8 af[3];
        #pragma unroll
        for (int dt = 0; dt < 3; ++dt) {
            int tp = tw + r + dt;        // A m = lane&15 = r
            int oct = quad ^ (tp & 3);
            af[dt] = *(const short8*)&act[((fh * 66) + tp) * 32 + oct * 8];
        }
        #pragma unroll
        for (int df = 0; df < 3; ++df) {
            int rel = fh - df;           // f_out - f0
            if (rel < 0 || rel >= 8) continue;
            #pragma unroll
            for (int dt = 0; dt < 3; ++dt)
                #pragma unroll
                for (int ct = 0; ct < 2; ++ct)
                    acc[rel][ct] = __builtin_amdgcn_mfma_f32_16x16x32_bf16(
                        af[dt], bfrag[df][dt][ct], acc[rel][ct], 0, 0, 0);
        }
    }

    // epilogue: D row = quad*4+reg -> t offset, col = r -> co (within ct)
    #pragma unroll
    for (int rel = 0; rel < 8; ++rel)
        #pragma unroll
        for (int ct = 0; ct < 2; ++ct) {
            int f  = f0 + rel;
            int co = ct * 16 + r;
            size_t base = (((size_t)b * 32 + co) * 64 + f) * 512;
            float bs = bias[co];
            #pragma unroll
            for (int reg = 0; reg < 4; ++reg) {
                int t = t0 + tw + quad * 4 + reg;
                float v = acc[rel][ct][reg] + bs;
                if (res) v += res[base + t];
                out[base + t] = v;
            }
        }
}

// ---------------- transpose (b,c,f,t) f32 -> A[(t*16+b)][(c*64+f)] bf16 ----------------
__global__ __launch_bounds__(256) void transpose_k(const float* __restrict__ X, u16* __restrict__ A) {
    __shared__ float tile[64][65];
    int t0 = blockIdx.x * 64;
    int c  = blockIdx.y;
    int b  = blockIdx.z;
    const float* p = X + (((size_t)b * 32 + c) * 64) * 512 + t0;
    #pragma unroll
    for (int i = 0; i < 16; ++i) {
        int f = i * 4 + (threadIdx.x >> 6);
        int t = threadIdx.x & 63;
        tile[f][t] = p[(size_t)f * 512 + t];
    }
    __syncthreads();
    #pragma unroll
    for (int i = 0; i < 16; ++i) {
        int t = i * 4 + (threadIdx.x >> 6);
        int f = threadIdx.x & 63;
        A[((size_t)(t0 + t) * 16 + b) * 2048 + c * 64 + f] = f2bf(tile[f][t]);
    }
}

// ---------------- row layernorm, f32 in -> bf16 out ----------------
__global__ __launch_bounds__(256) void lnlast_k(const float* __restrict__ X, u16* __restrict__ Y,
                                                const float* __restrict__ g, const float* __restrict__ bt,
                                                int width) {
    int row = blockIdx.x;
    const float* p = X + (size_t)row * width;
    float s = 0.f, s2 = 0.f;
    for (int i = threadIdx.x; i < width; i += 256) { float v = p[i]; s += v; s2 += v * v; }
    #pragma unroll
    for (int off = 32; off; off >>= 1) { s += __shfl_down(s, off); s2 += __shfl_down(s2, off); }
    __shared__ float red[4][2];
    int wv = threadIdx.x >> 6;
    if ((threadIdx.x & 63) == 0) { red[wv][0] = s; red[wv][1] = s2; }
    __syncthreads();
    if (threadIdx.x == 0) {
        float a = 0.f, b2 = 0.f;
        for (int i = 0; i < 4; ++i) { a += red[i][0]; b2 += red[i][1]; }
        float m = a / width;
        float var = fmaxf(b2 / width - m * m, 0.f);
        red[0][0] = m; red[0][1] = rsqrtf(var + 1e-5f);
    }
    __syncthreads();
    float m = red[0][0], rs = red[0][1];
    u16* q = Y + (size_t)row * width;
    for (int i = threadIdx.x; i < width; i += 256)
        q[i] = f2bf((p[i] - m) * rs * g[i] + bt[i]);
}

// ---------------- MFMA bf16 GEMM: C = A@B (+bias, relu). B dual-dtype, bofs in elements ----
__global__ __launch_bounds__(256) void gemm_k(const u16* __restrict__ A, int lda,
                                              const void* __restrict__ B, int ldb, int bofs,
                                              float* __restrict__ C, int ldc,
                                              const float* __restrict__ bias, int relu, int K,
                                              const int* __restrict__ flag) {
    int isf32 = *flag;
    __shared__ u16 As[64 * 32];  // [m][k]
    __shared__ u16 Bs[64 * 32];  // [n][k]
    int tid  = threadIdx.x;
    int bm   = blockIdx.x * 64;
    int bn   = blockIdx.y * 64;
    int wave = tid >> 6;
    int lane = tid & 63;
    int quad = lane >> 4;
    int r    = lane & 15;
    int wm   = (wave >> 1) * 32;
    int wn   = (wave & 1) * 32;
    floatx4 acc[2][2];
    #pragma unroll
    for (int i = 0; i < 2; ++i)
        #pragma unroll
        for (int j = 0; j < 2; ++j)
            #pragma unroll
            for (int k = 0; k < 4; ++k) acc[i][j][k] = 0.f;

    int arow = tid >> 2, aseg = (tid & 3) * 8;
    int brow = tid >> 3, bseg = (tid & 7) * 8;

    for (int k0 = 0; k0 < K; k0 += 32) {
        uint4 av = *(const uint4*)(A + (size_t)(bm + arow) * lda + k0 + aseg);
        *(uint4*)(As + arow * 32 + aseg) = av;
        size_t boff = (size_t)(k0 + brow) * ldb + bofs + bn + bseg;
        if (isf32) {
            const float* Bf = (const float*)B;
            float4 v0 = *(const float4*)(Bf + boff);
            float4 v1 = *(const float4*)(Bf + boff + 4);
            Bs[(bseg + 0) * 32 + brow] = f2bf(v0.x);
            Bs[(bseg + 1) * 32 + brow] = f2bf(v0.y);
            Bs[(bseg + 2) * 32 + brow] = f2bf(v0.z);
            Bs[(bseg + 3) * 32 + brow] = f2bf(v0.w);
            Bs[(bseg + 4) * 32 + brow] = f2bf(v1.x);
            Bs[(bseg + 5) * 32 + brow] = f2bf(v1.y);
            Bs[(bseg + 6) * 32 + brow] = f2bf(v1.z);
            Bs[(bseg + 7) * 32 + brow] = f2bf(v1.w);
        } else {
            const u16* Bh = (const u16*)B;
            union { uint4 v; u16 e[8]; } bb;
            bb.v = *(const uint4*)(Bh + boff);
            #pragma unroll
            for (int j = 0; j < 8; ++j) Bs[(bseg + j) * 32 + brow] = bb.e[j];
        }
        __syncthreads();
        short8 af[2], bf[2];
        #pragma unroll
        for (int mi = 0; mi < 2; ++mi) af[mi] = *(const short8*)(As + (wm + mi * 16 + r) * 32 + quad * 8);
        #pragma unroll
        for (int ni = 0; ni < 2; ++ni) bf[ni] = *(const short8*)(Bs + (wn + ni * 16 + r) * 32 + quad * 8);
        #pragma unroll
        for (int mi = 0; mi < 2; ++mi)
            #pragma unroll
            for (int ni = 0; ni < 2; ++ni)
                acc[mi][ni] = __builtin_amdgcn_mfma_f32_16x16x32_bf16(af[mi], bf[ni], acc[mi][ni], 0, 0, 0);
        __syncthreads();
    }
    #pragma unroll
    for (int mi = 0; mi < 2; ++mi)
        #pragma unroll
        for (int ni = 0; ni < 2; ++ni) {
            int col = bn + wn + ni * 16 + r;
            #pragma unroll
            for (int reg = 0; reg < 4; ++reg) {
                int row = bm + wm + mi * 16 + quad * 4 + reg;
                float v = acc[mi][ni][reg];
                if (bias) v += bias[col];
                if (relu) v = fmaxf(v, 0.f);
                C[(size_t)row * ldc + col] = v;
            }
        }
}

// ---------------- SRU recurrence, one 256-step chunk, both dirs ----------------
#define TC 256
__global__ __launch_bounds__(256) void scan_k(const float* __restrict__ Uf, const float* __restrict__ Ub,
                                              const float* __restrict__ Xp, float* __restrict__ Xn,
                                              float* __restrict__ cstate, const float* __restrict__ vv,
                                              const float* __restrict__ bb, int t0f, int t0b, int init) {
    int gid = blockIdx.x * 256 + threadIdx.x;  // 16384
    int d  = gid >> 13;
    int b  = (gid >> 9) & 15;
    int h  = gid & 511;
    float v0 = vv[(d * 2 + 0) * 512 + h];
    float v1 = vv[(d * 2 + 1) * 512 + h];
    float b0 = bb[(d * 2 + 0) * 512 + h];
    float b1 = bb[(d * 2 + 1) * 512 + h];
    const float* u  = (d ? Ub : Uf) + (size_t)b * 1536 + h;
    int t0 = d ? t0b : t0f;
    const float* xb = Xp + (size_t)b * 1024 + d * 512 + h;
    float*       ob = Xn + (size_t)b * 1024 + d * 512 + h;
    float c = init ? 0.f : cstate[gid];
    for (int s = 0; s < TC; ++s) {
        int sl = d ? (TC - 1 - s) : s;
        size_t ro = (size_t)sl * 16 * 1536;
        size_t xo = (size_t)(t0 + sl) * 16 * 1024;
        float u0 = u[ro];
        float fp = u[ro + 512]  + b0;
        float rp = u[ro + 1024] + b1;
        float xr = xb[xo];
        float f = 1.f / (1.f + __expf(-(fp + v0 * c)));
        float r = 1.f / (1.f + __expf(-(rp + v1 * c)));
        c = f * c + (1.f - f) * u0;
        float th = 1.f - 2.f / (__expf(2.f * c) + 1.f);  // tanh(c)
        ob[xo] = r * th + (1.f - r) * xr;
    }
    cstate[gid] = c;
}

// ---------------- classifier head ----------------
__global__ __launch_bounds__(256) void cls2_k(const float* __restrict__ FC1, const float* __restrict__ W2,
                                              const float* __restrict__ b2, void* __restrict__ out,
                                              const int* __restrict__ flag) {
    int isf32 = *flag;
    int row = blockIdx.x * 4 + (threadIdx.x >> 6);
    int v   = threadIdx.x & 63;
    if (v >= 29) return;
    const float* p = FC1 + (size_t)row * 512;
    float acc = 0.f;
    for (int k = 0; k < 512; ++k) acc = fmaf(p[k], W2[k * 29 + v], acc);
    acc += b2[v];
    int t = row >> 4, b = row & 15;
    size_t oi = ((size_t)b * 512 + t) * 29 + v;
    if (isf32) ((float*)out)[oi] = acc;
    else       ((u16*)out)[oi]   = f2bf(acc);
}

// ---------------- launch ----------------
extern "C" void kernel_launch(void* const* d_in, const int* in_sizes, int n_in,
                              void* d_out, int out_size, void* d_ws, size_t ws_size,
                              hipStream_t stream) {
    const void* x        = d_in[0];
    const void* proj_w   = d_in[11];
    const void* sru_w    = d_in[12];
    const void* cls_w1   = d_in[19];

    float* ws = (float*)d_ws;
    const size_t O_X    = 0;
    const size_t O_C    = 16777216;
    const size_t O_ST_M = 33554432;
    const size_t O_ST_R = 33816576;
    const size_t O_CST  = 34078720;
    const size_t O_PARK = 34095104;
    const size_t O_FLAG = 34187552;
    const size_t TOTAL  = 34187568;   // 130.4 MiB
    if (ws_size < TOTAL * sizeof(float)) {
        fill_k<<<(out_size + 255) / 256, 256, 0, stream>>>((float*)d_out, out_size);
        return;  // diagnostic: absmax ~1e6 => ws too small
    }

    u16*   Abf = (u16*)(ws + O_C);
    float* XP0 = ws + 25165824;
    u16*   XL  = (u16*)(ws + 0);
    float* XP1 = ws + 4194304;
    float* Uf  = ws + 12582912;
    float* Ub  = ws + 18874368;
    float* FC1 = ws + 12582912;
    float* X   = ws + O_X;
    float* C   = ws + O_C;
    float* SM  = ws + O_ST_M;
    float* SR  = ws + O_ST_R;
    float* CST = ws + O_CST;
    float* PK  = ws + O_PARK;
    int*   FLG = (int*)(ws + O_FLAG);

    float* p_cnn_w = PK + 0;      float* p_cnn_b = PK + 288;
    float* p_rw1   = PK + 320;    float* p_rb1   = PK + 27968;
    float* p_rw2   = PK + 28064;  float* p_rb2   = PK + 55712;
    float* p_l1g   = PK + 55808;  float* p_l1b   = PK + 56000;
    float* p_l2g   = PK + 56192;  float* p_l2b   = PK + 56384;
    float* p_sv    = PK + 56576;  float* p_sb    = PK + 62720;
    float* p_slng  = PK + 68864;  float* p_slnb  = PK + 71936;
    float* p_clng  = PK + 75008;  float* p_clnb  = PK + 76032;
    float* p_cb1   = PK + 77056;  float* p_cw2   = PK + 77568;
    float* p_cb2   = PK + 92416;

    sniff_k<<<1, 256, 0, stream>>>((const u16*)x, FLG);

    CvtArgs ca;
    const int srcidx[19] = {1,2,3,4,5,6,7,8,9,10,13,14,15,16,17,18,20,21,22};
    const int lens[19]   = {288,32,27648,96,27648,96,192,192,192,192,6144,6144,3072,3072,1024,1024,512,14848,29};
    const int offs[19]   = {0,288,320,27968,28064,55712,55808,56000,56192,56384,56576,62720,68864,71936,75008,76032,77056,77568,92416};
    for (int i = 0; i < 19; ++i) { ca.src[i] = d_in[srcidx[i]]; ca.len[i] = lens[i]; ca.off[i] = offs[i]; }
    cvtall_k<<<dim3(108, 19), 256, 0, stream>>>(ca, PK, FLG);

    conv1_k<<<65536, 256, 0, stream>>>(x, p_cnn_w, p_cnn_b, X, FLG);

    for (int i = 0; i < 3; ++i) {
        stats_k<<<1024, 256, 0, stream>>>(X, SM, SR);
        convm_k<<<dim3(8, 8, 16), 256, 0, stream>>>(X, C, SM, SR, p_l1g + i * 64, p_l1b + i * 64,
                                                    p_rw1 + i * 9216, p_rb1 + i * 32, nullptr);
        stats_k<<<1024, 256, 0, stream>>>(C, SM, SR);
        convm_k<<<dim3(8, 8, 16), 256, 0, stream>>>(C, X, SM, SR, p_l2g + i * 64, p_l2b + i * 64,
                                                    p_rw2 + i * 9216, p_rb2 + i * 32, X);
    }

    transpose_k<<<dim3(8, 32, 16), 256, 0, stream>>>(X, Abf);
    gemm_k<<<dim3(128, 16), 256, 0, stream>>>(Abf, 2048, proj_w, 1024, 0, XP0, 1024, nullptr, 0, 2048, FLG);

    float* cur = XP0;
    float* nxt = XP1;
    for (int l = 0; l < 3; ++l) {
        lnlast_k<<<8192, 256, 0, stream>>>(cur, XL, p_slng + l * 1024, p_slnb + l * 1024, 1024);
        size_t lofs = (size_t)l * 3145728;
        for (int j = 0; j < 2; ++j) {
            int t0f = j * TC;
            int t0b = (1 - j) * TC;
            gemm_k<<<dim3(64, 24), 256, 0, stream>>>(XL + (size_t)t0f * 16 * 1024, 1024,
                                                     sru_w, 3072, (int)lofs, Uf, 1536, nullptr, 0, 1024, FLG);
            gemm_k<<<dim3(64, 24), 256, 0, stream>>>(XL + (size_t)t0b * 16 * 1024, 1024,
                                                     sru_w, 3072, (int)lofs + 1536, Ub, 1536, nullptr, 0, 1024, FLG);
            scan_k<<<64, 256, 0, stream>>>(Uf, Ub, cur, nxt, CST,
                                           p_sv + l * 2048, p_sb + l * 2048, t0f, t0b, j == 0);
        }
        float* tmp = cur; cur = nxt; nxt = tmp;
    }

    lnlast_k<<<8192, 256, 0, stream>>>(cur, XL, p_clng, p_clnb, 1024);
    gemm_k<<<dim3(128, 8), 256, 0, stream>>>(XL, 1024, cls_w1, 512, 0, FC1, 512, p_cb1, 1, 1024, FLG);
    cls2_k<<<2048, 256, 0, stream>>>(FC1, p_cw2, p_cb2, d_out, FLG);
}

// Round 5
// 2251.096 us; speedup vs baseline: 2.0778x; 1.2264x over previous
//
#include <hip/hip_runtime.h>

typedef unsigned short u16;
typedef __attribute__((ext_vector_type(8))) short short8;
typedef __attribute__((ext_vector_type(4))) float floatx4;

__device__ __forceinline__ float bf2f(u16 u) {
    union { unsigned int i; float f; } v; v.i = ((unsigned int)u) << 16; return v.f;
}
__device__ __forceinline__ u16 f2bf(float f) {
    union { float f; unsigned int i; } v; v.f = f;
    unsigned int i = v.i + 0x7fffu + ((v.i >> 16) & 1u);  // RNE
    return (u16)(i >> 16);
}

// async global->LDS, 16B per lane; LDS dest must be uniform + lane*16
#define GLL(g, l) __builtin_amdgcn_global_load_lds( \
    (const __attribute__((address_space(1))) void*)(g), \
    (__attribute__((address_space(3))) void*)(l), 16, 0, 0)

// ---------------- dtype sniffer: flag=1 means inputs are float32 ----------------
__global__ __launch_bounds__(256) void sniff_k(const u16* __restrict__ x, int* __restrict__ flag) {
    __shared__ int red[4];
    int cnt = 0;
    for (int i = 0; i < 16; ++i) {
        u16 v = x[(threadIdx.x * 16 + i) * 2];
        int e = (v >> 7) & 0xFF;
        if (e >= 110 && e <= 135) cnt++;
    }
    #pragma unroll
    for (int off = 32; off; off >>= 1) cnt += __shfl_down(cnt, off);
    if ((threadIdx.x & 63) == 0) red[threadIdx.x >> 6] = cnt;
    __syncthreads();
    if (threadIdx.x == 0) {
        int tot = red[0] + red[1] + red[2] + red[3];
        *flag = (tot < 2048) ? 1 : 0;
    }
}

__device__ __forceinline__ float ldin(const void* p, size_t i, int isf32) {
    return isf32 ? ((const float*)p)[i] : bf2f(((const u16*)p)[i]);
}

// ---------------- canonicalize all params to f32 park (one launch) ----------------
struct CvtArgs {
    const void* src[19];
    int len[19];
    int off[19];
};
__global__ __launch_bounds__(256) void cvtall_k(CvtArgs a, float* __restrict__ dst,
                                                const int* __restrict__ flag) {
    int isf32 = *flag;
    int seg = blockIdx.y;
    int n = a.len[seg];
    const void* s = a.src[seg];
    float* d = dst + a.off[seg];
    for (int i = blockIdx.x * 256 + threadIdx.x; i < n; i += gridDim.x * 256)
        d[i] = ldin(s, i, isf32);
}

// ---------------- weight transpose: W[K][N] (dual dtype) -> Wt[N][K] bf16 ----------------
__global__ __launch_bounds__(256) void wtr_k(const void* __restrict__ W, int ldw, size_t wofs,
                                             u16* __restrict__ Wt, int ldt,
                                             const int* __restrict__ flag) {
    int isf32 = *flag;
    __shared__ u16 t[64][65];
    int k0 = blockIdx.x * 64, n0 = blockIdx.y * 64;
    int tid = threadIdx.x;
    #pragma unroll
    for (int i = 0; i < 16; ++i) {
        int kk = i * 4 + (tid >> 6), nn = tid & 63;
        t[kk][nn] = f2bf(ldin(W, wofs + (size_t)(k0 + kk) * ldw + n0 + nn, isf32));
    }
    __syncthreads();
    #pragma unroll
    for (int i = 0; i < 16; ++i) {
        int nn = i * 4 + (tid >> 6), kk = tid & 63;
        Wt[(size_t)(n0 + nn) * ldt + k0 + kk] = t[kk][nn];
    }
}

// ---------------- guard diagnostic fill ----------------
__global__ __launch_bounds__(256) void fill_k(float* __restrict__ p, int n) {
    int i = blockIdx.x * 256 + threadIdx.x;
    if (i < n) p[i] = 1.0e6f;
}

// ---------------- conv stem: 1->32, k3 s2 p1 ----------------
__global__ __launch_bounds__(256) void conv1_k(const void* __restrict__ x, const float* __restrict__ w,
                                               const float* __restrict__ bias, float* __restrict__ out,
                                               const int* __restrict__ flag) {
    int isf32 = *flag;
    int idx = blockIdx.x * 256 + threadIdx.x;
    int t  = idx & 511;
    int f  = (idx >> 9) & 63;
    int co = (idx >> 15) & 31;
    int b  = idx >> 20;
    size_t xb = (size_t)b * 128 * 1024;
    float acc = bias[co];
    #pragma unroll
    for (int df = 0; df < 3; ++df) {
        int fi = 2 * f + df - 1;
        if (fi < 0 || fi >= 128) continue;
        #pragma unroll
        for (int dt = 0; dt < 3; ++dt) {
            int ti = 2 * t + dt - 1;
            if (ti < 0 || ti >= 1024) continue;
            acc += w[co * 9 + df * 3 + dt] * ldin(x, xb + (size_t)fi * 1024 + ti, isf32);
        }
    }
    out[idx] = acc;
}

// ---------------- LN-over-f stats ----------------
__global__ __launch_bounds__(256) void stats_k(const float* __restrict__ X, float* __restrict__ sm,
                                               float* __restrict__ sr) {
    int idx = blockIdx.x * 256 + threadIdx.x;  // 16*32*512
    int t  = idx & 511;
    int bc = idx >> 9;
    const float* p = X + (size_t)bc * 64 * 512 + t;
    float s = 0.f, s2 = 0.f;
    #pragma unroll 8
    for (int f = 0; f < 64; ++f) { float v = p[f * 512]; s += v; s2 += v * v; }
    float m  = s * (1.f / 64.f);
    float var = fmaxf(s2 * (1.f / 64.f) - m * m, 0.f);
    sm[idx] = m;
    sr[idx] = rsqrtf(var + 1e-5f);
}

// ---------------- fused LN+ReLU+conv32 via MFMA (implicit GEMM) ----------------
__global__ __launch_bounds__(256) void convm_k(const float* __restrict__ in, float* __restrict__ out,
                                               const float* __restrict__ sm, const float* __restrict__ sr,
                                               const float* __restrict__ g, const float* __restrict__ be,
                                               const float* __restrict__ w, const float* __restrict__ bias,
                                               const float* __restrict__ res) {
    __shared__ u16 act[10 * 66 * 32];  // 42240 B
    int f0 = blockIdx.x * 8;
    int t0 = blockIdx.y * 64;
    int b  = blockIdx.z;
    const float* inb = in + (size_t)b * 32 * 64 * 512;

    int lane = threadIdx.x & 63;
    int wv   = threadIdx.x >> 6;
    int quad = lane >> 4;
    int r    = lane & 15;

    short8 bfrag[3][3][2];
    #pragma unroll
    for (int df = 0; df < 3; ++df)
        #pragma unroll
        for (int dt = 0; dt < 3; ++dt)
            #pragma unroll
            for (int ct = 0; ct < 2; ++ct) {
                short8 v;
                #pragma unroll
                for (int j = 0; j < 8; ++j) {
                    int co = ct * 16 + r, ci = quad * 8 + j;
                    v[j] = (short)f2bf(w[(co * 32 + ci) * 9 + df * 3 + dt]);
                }
                bfrag[df][dt][ct] = v;
            }

    for (int i = threadIdx.x; i < 660; i += 256) {
        int fp = i / 66;
        int tp = i % 66;
        int gf = f0 + fp - 1, gt = t0 + tp - 1;
        int sw = (tp & 3);
        u16* dstrow = &act[(fp * 66 + tp) * 32];
        if (gf < 0 || gf >= 64 || gt < 0 || gt >= 512) {
            #pragma unroll
            for (int o = 0; o < 4; ++o) {
                short8 z = {0,0,0,0,0,0,0,0};
                *(short8*)&dstrow[(o ^ sw) * 8] = z;
            }
        } else {
            float gg = g[gf], bb2 = be[gf];
            #pragma unroll
            for (int o = 0; o < 4; ++o) {
                short8 v;
                #pragma unroll
                for (int j = 0; j < 8; ++j) {
                    int ci = o * 8 + j;
                    float xv = inb[((size_t)ci * 64 + gf) * 512 + gt];
                    int si = (b * 32 + ci) * 512 + gt;
                    v[j] = (short)f2bf(fmaxf((xv - sm[si]) * sr[si] * gg + bb2, 0.f));
                }
                *(short8*)&dstrow[(o ^ sw) * 8] = v;
            }
        }
    }
    __syncthreads();

    floatx4 acc[8][2];
    #pragma unroll
    for (int i = 0; i < 8; ++i)
        #pragma unroll
        for (int j = 0; j < 2; ++j)
            #pragma unroll
            for (int k = 0; k < 4; ++k) acc[i][j][k] = 0.f;

    int tw = wv * 16;
    #pragma unroll
    for (int fh = 0; fh < 10; ++fh) {
        short8 af[3];
        #pragma unroll
        for (int dt = 0; dt < 3; ++dt) {
            int tp = tw + r + dt;
            int oct = quad ^ (tp & 3);
            af[dt] = *(const short8*)&act[((fh * 66) + tp) * 32 + oct * 8];
        }
        #pragma unroll
        for (int df = 0; df < 3; ++df) {
            int rel = fh - df;
            if (rel < 0 || rel >= 8) continue;
            #pragma unroll
            for (int dt = 0; dt < 3; ++dt)
                #pragma unroll
                for (int ct = 0; ct < 2; ++ct)
                    acc[rel][ct] = __builtin_amdgcn_mfma_f32_16x16x32_bf16(
                        af[dt], bfrag[df][dt][ct], acc[rel][ct], 0, 0, 0);
        }
    }

    #pragma unroll
    for (int rel = 0; rel < 8; ++rel)
        #pragma unroll
        for (int ct = 0; ct < 2; ++ct) {
            int f  = f0 + rel;
            int co = ct * 16 + r;
            size_t base = (((size_t)b * 32 + co) * 64 + f) * 512;
            float bs = bias[co];
            #pragma unroll
            for (int reg = 0; reg < 4; ++reg) {
                int t = t0 + tw + quad * 4 + reg;
                float v = acc[rel][ct][reg] + bs;
                if (res) v += res[base + t];
                out[base + t] = v;
            }
        }
}

// ---------------- transpose (b,c,f,t) f32 -> A[(t*16+b)][(c*64+f)] bf16 ----------------
__global__ __launch_bounds__(256) void transpose_k(const float* __restrict__ X, u16* __restrict__ A) {
    __shared__ float tile[64][65];
    int t0 = blockIdx.x * 64;
    int c  = blockIdx.y;
    int b  = blockIdx.z;
    const float* p = X + (((size_t)b * 32 + c) * 64) * 512 + t0;
    #pragma unroll
    for (int i = 0; i < 16; ++i) {
        int f = i * 4 + (threadIdx.x >> 6);
        int t = threadIdx.x & 63;
        tile[f][t] = p[(size_t)f * 512 + t];
    }
    __syncthreads();
    #pragma unroll
    for (int i = 0; i < 16; ++i) {
        int t = i * 4 + (threadIdx.x >> 6);
        int f = threadIdx.x & 63;
        A[((size_t)(t0 + t) * 16 + b) * 2048 + c * 64 + f] = f2bf(tile[f][t]);
    }
}

// ---------------- row layernorm, f32 in -> bf16 out ----------------
__global__ __launch_bounds__(256) void lnlast_k(const float* __restrict__ X, u16* __restrict__ Y,
                                                const float* __restrict__ g, const float* __restrict__ bt,
                                                int width) {
    int row = blockIdx.x;
    const float* p = X + (size_t)row * width;
    float s = 0.f, s2 = 0.f;
    for (int i = threadIdx.x; i < width; i += 256) { float v = p[i]; s += v; s2 += v * v; }
    #pragma unroll
    for (int off = 32; off; off >>= 1) { s += __shfl_down(s, off); s2 += __shfl_down(s2, off); }
    __shared__ float red[4][2];
    int wv = threadIdx.x >> 6;
    if ((threadIdx.x & 63) == 0) { red[wv][0] = s; red[wv][1] = s2; }
    __syncthreads();
    if (threadIdx.x == 0) {
        float a = 0.f, b2 = 0.f;
        for (int i = 0; i < 4; ++i) { a += red[i][0]; b2 += red[i][1]; }
        float m = a / width;
        float var = fmaxf(b2 / width - m * m, 0.f);
        red[0][0] = m; red[0][1] = rsqrtf(var + 1e-5f);
    }
    __syncthreads();
    float m = red[0][0], rs = red[0][1];
    u16* q = Y + (size_t)row * width;
    for (int i = threadIdx.x; i < width; i += 256)
        q[i] = f2bf((p[i] - m) * rs * g[i] + bt[i]);
}

// ---------------- m97-style MFMA GEMM: C = A @ Bt^T, 128x128 tile, BK=32 ----------------
// A bf16 [M][lda], Bt bf16 [N][ldb] (B transposed), C f32 [M][ldc].
// Column tiles with bn >= nsplit switch to (A2, C2) with col -= nsplit (fused dual-GEMM).
__global__ __launch_bounds__(256) void gemm_bt(const u16* __restrict__ A, const u16* __restrict__ A2,
                                               int lda, const u16* __restrict__ Bt, int ldb,
                                               float* __restrict__ C, float* __restrict__ C2,
                                               int ldc, int nsplit,
                                               const float* __restrict__ bias, int relu, int K) {
    __shared__ u16 As[128 * 32];
    __shared__ u16 Bs[128 * 32];
    int tid  = threadIdx.x;
    int bm   = blockIdx.x * 128;
    int bn   = blockIdx.y * 128;
    const u16* Ab = A;
    float* Cb = C;
    int cn = bn;
    if (bn >= nsplit) { Ab = A2; Cb = C2; cn = bn - nsplit; }

    int lane = tid & 63;
    int wv   = tid >> 6;
    int quad = lane >> 4;
    int r    = lane & 15;
    int wm   = (wv >> 1) * 64;
    int wn   = (wv & 1) * 64;

    floatx4 acc[4][4];
    #pragma unroll
    for (int i = 0; i < 4; ++i)
        #pragma unroll
        for (int j = 0; j < 4; ++j)
            #pragma unroll
            for (int k = 0; k < 4; ++k) acc[i][j][k] = 0.f;

    int row0 = tid >> 2;            // 0..63
    int ks0  = (tid & 3) * 8;       // k-seg in elements (16B)
    const u16* Abase = Ab + (size_t)(bm + row0) * lda + ks0;
    const u16* Abase2 = Ab + (size_t)(bm + 64 + row0) * lda + ks0;
    const u16* Bbase = Bt + (size_t)(bn + row0) * ldb + ks0;
    const u16* Bbase2 = Bt + (size_t)(bn + 64 + row0) * ldb + ks0;
    u16* AsD  = As + tid * 8;
    u16* AsD2 = As + 2048 + tid * 8;
    u16* BsD  = Bs + tid * 8;
    u16* BsD2 = Bs + 2048 + tid * 8;

    for (int k0 = 0; k0 < K; k0 += 32) {
        GLL(Abase + k0, AsD);
        GLL(Abase2 + k0, AsD2);
        GLL(Bbase + k0, BsD);
        GLL(Bbase2 + k0, BsD2);
        __syncthreads();   // drains vmcnt -> LDS valid
        short8 af[4], bf[4];
        #pragma unroll
        for (int mi = 0; mi < 4; ++mi) af[mi] = *(const short8*)&As[(wm + mi * 16 + r) * 32 + quad * 8];
        #pragma unroll
        for (int ni = 0; ni < 4; ++ni) bf[ni] = *(const short8*)&Bs[(wn + ni * 16 + r) * 32 + quad * 8];
        #pragma unroll
        for (int mi = 0; mi < 4; ++mi)
            #pragma unroll
            for (int ni = 0; ni < 4; ++ni)
                acc[mi][ni] = __builtin_amdgcn_mfma_f32_16x16x32_bf16(af[mi], bf[ni], acc[mi][ni], 0, 0, 0);
        __syncthreads();
    }

    // C/D layout: col = lane&15, row = quad*4 + reg
    #pragma unroll
    for (int mi = 0; mi < 4; ++mi)
        #pragma unroll
        for (int ni = 0; ni < 4; ++ni) {
            int col = cn + wn + ni * 16 + r;
            float bs = bias ? bias[col] : 0.f;
            #pragma unroll
            for (int reg = 0; reg < 4; ++reg) {
                int row = bm + wm + mi * 16 + quad * 4 + reg;
                float v = acc[mi][ni][reg] + bs;
                if (relu) v = fmaxf(v, 0.f);
                Cb[(size_t)row * ldc + col] = v;
            }
        }
}

// ---------------- SRU recurrence, one TC-step chunk, both dirs ----------------
#define TC 128
__global__ __launch_bounds__(256) void scan_k(const float* __restrict__ Uf, const float* __restrict__ Ub,
                                              const float* __restrict__ Xp, float* __restrict__ Xn,
                                              float* __restrict__ cstate, const float* __restrict__ vv,
                                              const float* __restrict__ bb, int t0f, int t0b, int init) {
    int gid = blockIdx.x * 256 + threadIdx.x;  // 16384
    int d  = gid >> 13;
    int b  = (gid >> 9) & 15;
    int h  = gid & 511;
    float v0 = vv[(d * 2 + 0) * 512 + h];
    float v1 = vv[(d * 2 + 1) * 512 + h];
    float b0 = bb[(d * 2 + 0) * 512 + h];
    float b1 = bb[(d * 2 + 1) * 512 + h];
    const float* u  = (d ? Ub : Uf) + (size_t)b * 1536 + h;
    int t0 = d ? t0b : t0f;
    const float* xb = Xp + (size_t)b * 1024 + d * 512 + h;
    float*       ob = Xn + (size_t)b * 1024 + d * 512 + h;
    float c = init ? 0.f : cstate[gid];
    for (int s = 0; s < TC; ++s) {
        int sl = d ? (TC - 1 - s) : s;
        size_t ro = (size_t)sl * 16 * 1536;
        size_t xo = (size_t)(t0 + sl) * 16 * 1024;
        float u0 = u[ro];
        float fp = u[ro + 512]  + b0;
        float rp = u[ro + 1024] + b1;
        float xr = xb[xo];
        float f = 1.f / (1.f + __expf(-(fp + v0 * c)));
        float r = 1.f / (1.f + __expf(-(rp + v1 * c)));
        c = f * c + (1.f - f) * u0;
        float th = 1.f - 2.f / (__expf(2.f * c) + 1.f);  // tanh(c)
        ob[xo] = r * th + (1.f - r) * xr;
    }
    cstate[gid] = c;
}

// ---------------- classifier head ----------------
__global__ __launch_bounds__(256) void cls2_k(const float* __restrict__ FC1, const float* __restrict__ W2,
                                              const float* __restrict__ b2, void* __restrict__ out,
                                              const int* __restrict__ flag) {
    int isf32 = *flag;
    int row = blockIdx.x * 4 + (threadIdx.x >> 6);
    int v   = threadIdx.x & 63;
    if (v >= 29) return;
    const float* p = FC1 + (size_t)row * 512;
    float acc = 0.f;
    for (int k = 0; k < 512; ++k) acc = fmaf(p[k], W2[k * 29 + v], acc);
    acc += b2[v];
    int t = row >> 4, b = row & 15;
    size_t oi = ((size_t)b * 512 + t) * 29 + v;
    if (isf32) ((float*)out)[oi] = acc;
    else       ((u16*)out)[oi]   = f2bf(acc);
}

// ---------------- launch ----------------
extern "C" void kernel_launch(void* const* d_in, const int* in_sizes, int n_in,
                              void* d_out, int out_size, void* d_ws, size_t ws_size,
                              hipStream_t stream) {
    const void* x        = d_in[0];
    const void* proj_w   = d_in[11];
    const void* sru_w    = d_in[12];
    const void* cls_w1   = d_in[19];

    float* ws = (float*)d_ws;
    const size_t O_X    = 0;
    const size_t O_C    = 16777216;
    const size_t O_ST_M = 33554432;
    const size_t O_ST_R = 33816576;
    const size_t O_CST  = 34078720;
    const size_t O_PARK = 34095104;
    const size_t O_FLAG = 34187552;
    const size_t TOTAL  = 34187568;   // 130.4 MiB
    if (ws_size < TOTAL * sizeof(float)) {
        fill_k<<<(out_size + 255) / 256, 256, 0, stream>>>((float*)d_out, out_size);
        return;  // diagnostic: absmax ~1e6 => ws too small
    }

    // lifetime-aliased regions (float offsets):
    u16*   Abf = (u16*)(ws + O_C);         // [16.78M, 25.17M) conv staging -> proj A
    float* XP0 = ws + 25165824;            // [25.17M, 33.55M) RNN ping
    u16*   XL  = (u16*)(ws + 0);           // [0, 4.19M)       LN output bf16
    float* XP1 = ws + 4194304;             // [4.19M, 12.58M)  RNN pong
    float* Uf  = ws + 12582912;            // [12.58M, 15.73M) u chunk fwd (2048x1536)
    float* Ub  = ws + 15728640;            // [15.73M, 18.87M) u chunk bwd
    u16*   BtS = (u16*)(ws + 18874368);    // [18.87M, 23.59M) sru B^T bf16, 3 x 3072x1024
    u16*   BtP = (u16*)(ws + 0);           // [0, 1.05M)  proj B^T bf16 (X dead, XL not yet)
    u16*   BtC = (u16*)(ws + O_ST_M);      // [33.55M, +0.26M) cls B^T bf16 (stats dead)
    float* FC1 = ws + 12582912;            // [12.58M, 16.78M) classifier (U dead)
    float* X   = ws + O_X;
    float* C   = ws + O_C;
    float* SM  = ws + O_ST_M;
    float* SR  = ws + O_ST_R;
    float* CST = ws + O_CST;
    float* PK  = ws + O_PARK;
    int*   FLG = (int*)(ws + O_FLAG);

    float* p_cnn_w = PK + 0;      float* p_cnn_b = PK + 288;
    float* p_rw1   = PK + 320;    float* p_rb1   = PK + 27968;
    float* p_rw2   = PK + 28064;  float* p_rb2   = PK + 55712;
    float* p_l1g   = PK + 55808;  float* p_l1b   = PK + 56000;
    float* p_l2g   = PK + 56192;  float* p_l2b   = PK + 56384;
    float* p_sv    = PK + 56576;  float* p_sb    = PK + 62720;
    float* p_slng  = PK + 68864;  float* p_slnb  = PK + 71936;
    float* p_clng  = PK + 75008;  float* p_clnb  = PK + 76032;
    float* p_cb1   = PK + 77056;  float* p_cw2   = PK + 77568;
    float* p_cb2   = PK + 92416;

    sniff_k<<<1, 256, 0, stream>>>((const u16*)x, FLG);

    CvtArgs ca;
    const int srcidx[19] = {1,2,3,4,5,6,7,8,9,10,13,14,15,16,17,18,20,21,22};
    const int lens[19]   = {288,32,27648,96,27648,96,192,192,192,192,6144,6144,3072,3072,1024,1024,512,14848,29};
    const int offs[19]   = {0,288,320,27968,28064,55712,55808,56000,56192,56384,56576,62720,68864,71936,75008,76032,77056,77568,92416};
    for (int i = 0; i < 19; ++i) { ca.src[i] = d_in[srcidx[i]]; ca.len[i] = lens[i]; ca.off[i] = offs[i]; }
    cvtall_k<<<dim3(108, 19), 256, 0, stream>>>(ca, PK, FLG);

    conv1_k<<<65536, 256, 0, stream>>>(x, p_cnn_w, p_cnn_b, X, FLG);

    for (int i = 0; i < 3; ++i) {
        stats_k<<<1024, 256, 0, stream>>>(X, SM, SR);
        convm_k<<<dim3(8, 8, 16), 256, 0, stream>>>(X, C, SM, SR, p_l1g + i * 64, p_l1b + i * 64,
                                                    p_rw1 + i * 9216, p_rb1 + i * 32, nullptr);
        stats_k<<<1024, 256, 0, stream>>>(C, SM, SR);
        convm_k<<<dim3(8, 8, 16), 256, 0, stream>>>(C, X, SM, SR, p_l2g + i * 64, p_l2b + i * 64,
                                                    p_rw2 + i * 9216, p_rb2 + i * 32, X);
    }

    // X -> Abf (bf16, GEMM-A layout); then X region is dead -> BtP may use it
    transpose_k<<<dim3(8, 32, 16), 256, 0, stream>>>(X, Abf);
    wtr_k<<<dim3(32, 16), 256, 0, stream>>>(proj_w, 1024, 0, BtP, 2048, FLG);   // [2048][1024] -> [1024][2048]
    // proj: C[8192,1024] = Abf[8192,2048] @ proj_w
    gemm_bt<<<dim3(64, 8), 256, 0, stream>>>(Abf, Abf, 2048, BtP, 2048, XP0, XP0, 1024,
                                             1 << 30, nullptr, 0, 2048);

    // Abf now dead -> BtS region usable; stats dead -> BtC usable
    for (int l = 0; l < 3; ++l)
        wtr_k<<<dim3(16, 48), 256, 0, stream>>>(sru_w, 3072, (size_t)l * 3145728,
                                                BtS + (size_t)l * 3145728, 1024, FLG);
    wtr_k<<<dim3(16, 8), 256, 0, stream>>>(cls_w1, 512, 0, BtC, 1024, FLG);

    float* cur = XP0;
    float* nxt = XP1;
    for (int l = 0; l < 3; ++l) {
        lnlast_k<<<8192, 256, 0, stream>>>(cur, XL, p_slng + l * 1024, p_slnb + l * 1024, 1024);
        const u16* Btl = BtS + (size_t)l * 3145728;
        for (int j = 0; j < 4; ++j) {
            int t0f = j * TC;
            int t0b = (3 - j) * TC;
            // fused fwd+bwd u-GEMM: cols [0,1536) fwd from rows t0f.., cols [1536,3072) bwd from rows t0b..
            gemm_bt<<<dim3(16, 24), 256, 0, stream>>>(XL + (size_t)t0f * 16 * 1024,
                                                      XL + (size_t)t0b * 16 * 1024, 1024,
                                                      Btl, 1024, Uf, Ub, 1536, 1536,
                                                      nullptr, 0, 1024);
            scan_k<<<64, 256, 0, stream>>>(Uf, Ub, cur, nxt, CST,
                                           p_sv + l * 2048, p_sb + l * 2048, t0f, t0b, j == 0);
        }
        float* tmp = cur; cur = nxt; nxt = tmp;
    }

    lnlast_k<<<8192, 256, 0, stream>>>(cur, XL, p_clng, p_clnb, 1024);
    gemm_bt<<<dim3(64, 4), 256, 0, stream>>>(XL, XL, 1024, BtC, 1024, FC1, FC1, 512,
                                             1 << 30, p_cb1, 1, 1024);
    cls2_k<<<2048, 256, 0, stream>>>(FC1, p_cw2, p_cb2, d_out, FLG);
}

// Round 6
// 1927.963 us; speedup vs baseline: 2.4261x; 1.1676x over previous
//
#include <hip/hip_runtime.h>

typedef unsigned short u16;
typedef unsigned int u32;
typedef __attribute__((ext_vector_type(8))) short short8;
typedef __attribute__((ext_vector_type(4))) float floatx4;

__device__ __forceinline__ float bf2f(u16 u) {
    union { unsigned int i; float f; } v; v.i = ((unsigned int)u) << 16; return v.f;
}
__device__ __forceinline__ u16 f2bf(float f) {
    union { float f; unsigned int i; } v; v.f = f;
    unsigned int i = v.i + 0x7fffu + ((v.i >> 16) & 1u);  // RNE
    return (u16)(i >> 16);
}

// async global->LDS, 16B per lane; LDS dest must be wave-uniform base + lane*16
#define GLL(g, l) __builtin_amdgcn_global_load_lds( \
    (const __attribute__((address_space(1))) void*)(g), \
    (__attribute__((address_space(3))) void*)(l), 16, 0, 0)

// Ha halo tensor: [b][f_idx 0..65][t_idx 0..513 (pad 514)][ci 0..31] bf16
#define HA_BSTRIDE 1085568  // 66*514*32

// ---------------- dtype sniffer: flag=1 means inputs are float32 ----------------
__global__ __launch_bounds__(256) void sniff_k(const u16* __restrict__ x, int* __restrict__ flag) {
    __shared__ int red[4];
    int cnt = 0;
    for (int i = 0; i < 16; ++i) {
        u16 v = x[(threadIdx.x * 16 + i) * 2];
        int e = (v >> 7) & 0xFF;
        if (e >= 110 && e <= 135) cnt++;
    }
    #pragma unroll
    for (int off = 32; off; off >>= 1) cnt += __shfl_down(cnt, off);
    if ((threadIdx.x & 63) == 0) red[threadIdx.x >> 6] = cnt;
    __syncthreads();
    if (threadIdx.x == 0) {
        int tot = red[0] + red[1] + red[2] + red[3];
        *flag = (tot < 2048) ? 1 : 0;
    }
}

__device__ __forceinline__ float ldin(const void* p, size_t i, int isf32) {
    return isf32 ? ((const float*)p)[i] : bf2f(((const u16*)p)[i]);
}

// ---------------- canonicalize all params to f32 park (one launch) ----------------
struct CvtArgs {
    const void* src[19];
    int len[19];
    int off[19];
};
__global__ __launch_bounds__(256) void cvtall_k(CvtArgs a, float* __restrict__ dst,
                                                const int* __restrict__ flag) {
    int isf32 = *flag;
    int seg = blockIdx.y;
    int n = a.len[seg];
    const void* s = a.src[seg];
    float* d = dst + a.off[seg];
    for (int i = blockIdx.x * 256 + threadIdx.x; i < n; i += gridDim.x * 256)
        d[i] = ldin(s, i, isf32);
}

// ---------------- weight transpose: W[K][N] (dual dtype) -> Wt[N][K] bf16 ----------------
__global__ __launch_bounds__(256) void wtr_k(const void* __restrict__ W, int ldw, size_t wofs,
                                             u16* __restrict__ Wt, int ldt,
                                             const int* __restrict__ flag) {
    int isf32 = *flag;
    __shared__ u16 t[64][65];
    int k0 = blockIdx.x * 64, n0 = blockIdx.y * 64;
    int tid = threadIdx.x;
    #pragma unroll
    for (int i = 0; i < 16; ++i) {
        int kk = i * 4 + (tid >> 6), nn = tid & 63;
        t[kk][nn] = f2bf(ldin(W, wofs + (size_t)(k0 + kk) * ldw + n0 + nn, isf32));
    }
    __syncthreads();
    #pragma unroll
    for (int i = 0; i < 16; ++i) {
        int nn = i * 4 + (tid >> 6), kk = tid & 63;
        Wt[(size_t)(n0 + nn) * ldt + k0 + kk] = t[kk][nn];
    }
}

// ---------------- zero / guard fill ----------------
__global__ __launch_bounds__(256) void zero_k(float4* __restrict__ p, int n4) {
    float4 z = {0.f, 0.f, 0.f, 0.f};
    for (int i = blockIdx.x * 256 + threadIdx.x; i < n4; i += gridDim.x * 256) p[i] = z;
}
__global__ __launch_bounds__(256) void fill_k(float* __restrict__ p, int n) {
    int i = blockIdx.x * 256 + threadIdx.x;
    if (i < n) p[i] = 1.0e6f;
}

// ---------------- conv stem: 1->32, k3 s2 p1 -> X f32 NCHW ----------------
__global__ __launch_bounds__(256) void conv1_k(const void* __restrict__ x, const float* __restrict__ w,
                                               const float* __restrict__ bias, float* __restrict__ out,
                                               const int* __restrict__ flag) {
    int isf32 = *flag;
    int idx = blockIdx.x * 256 + threadIdx.x;
    int t  = idx & 511;
    int f  = (idx >> 9) & 63;
    int co = (idx >> 15) & 31;
    int b  = idx >> 20;
    size_t xb = (size_t)b * 128 * 1024;
    float acc = bias[co];
    #pragma unroll
    for (int df = 0; df < 3; ++df) {
        int fi = 2 * f + df - 1;
        if (fi < 0 || fi >= 128) continue;
        #pragma unroll
        for (int dt = 0; dt < 3; ++dt) {
            int ti = 2 * t + dt - 1;
            if (ti < 0 || ti >= 1024) continue;
            acc += w[co * 9 + df * 3 + dt] * ldin(x, xb + (size_t)fi * 1024 + ti, isf32);
        }
    }
    out[idx] = acc;
}

// ---------------- LN-over-f stats (dual-dtype input, NCHW) ----------------
__global__ __launch_bounds__(256) void stats_k(const void* __restrict__ X, int isbf,
                                               float* __restrict__ sm, float* __restrict__ sr) {
    int idx = blockIdx.x * 256 + threadIdx.x;  // 16*32*512
    int t  = idx & 511;
    int bc = idx >> 9;
    size_t base = (size_t)bc * 64 * 512 + t;
    float s = 0.f, s2 = 0.f;
    #pragma unroll 8
    for (int f = 0; f < 64; ++f) {
        float v = isbf ? bf2f(((const u16*)X)[base + f * 512]) : ((const float*)X)[base + f * 512];
        s += v; s2 += v * v;
    }
    float m  = s * (1.f / 64.f);
    float var = fmaxf(s2 * (1.f / 64.f) - m * m, 0.f);
    sm[idx] = m;
    sr[idx] = rsqrtf(var + 1e-5f);
}

// ---------------- apply LN+ReLU: NCHW (f32|bf16) -> Ha NHWC halo bf16 ----------------
// grid (64 f, 16 b), 256 threads; each thread: one t per iter, all 32 ci.
__global__ __launch_bounds__(256) void apply_k(const void* __restrict__ in, int isbf,
                                               const float* __restrict__ sm, const float* __restrict__ sr,
                                               const float* __restrict__ g, const float* __restrict__ be,
                                               u16* __restrict__ Ha) {
    int f = blockIdx.x;
    int b = blockIdx.y;
    float gg = g[f], bb_ = be[f];
    for (int it = 0; it < 2; ++it) {
        int t = it * 256 + threadIdx.x;
        u32 pk[16];
        #pragma unroll
        for (int cp = 0; cp < 16; ++cp) {
            u32 w = 0;
            #pragma unroll
            for (int half = 0; half < 2; ++half) {
                int ci = cp * 2 + half;
                size_t xi = (((size_t)b * 32 + ci) * 64 + f) * 512 + t;
                float xv = isbf ? bf2f(((const u16*)in)[xi]) : ((const float*)in)[xi];
                int si = (b * 32 + ci) * 512 + t;
                float hv = fmaxf((xv - sm[si]) * sr[si] * gg + bb_, 0.f);
                w |= ((u32)f2bf(hv)) << (half * 16);
            }
            pk[cp] = w;
        }
        u32* orow = (u32*)(Ha + (size_t)b * HA_BSTRIDE + ((size_t)(f + 1) * 514 + (t + 1)) * 32);
        #pragma unroll
        for (int q = 0; q < 16; ++q) orow[q] = pk[q];
    }
}

// ---------------- conv32 k3 s1 p1 via MFMA, GLL staging from Ha ----------------
// grid (16 fb [tile 4], 8 tb [tile 64], 16 b), 256 threads (4 waves, t-subtile 16 each).
// res == nullptr: out is bf16 NCHW (C). res != nullptr: out f32 NCHW, += res.
__global__ __launch_bounds__(256) void convm_k(const u16* __restrict__ Ha, void* __restrict__ out,
                                               const float* __restrict__ w, const float* __restrict__ bias,
                                               const float* __restrict__ res) {
    __shared__ u16 act[6 * 66 * 32];  // 25344 B, [fp][tp][ci]
    int f0 = blockIdx.x * 4;
    int t0 = blockIdx.y * 64;
    int b  = blockIdx.z;
    const u16* Hb = Ha + (size_t)b * HA_BSTRIDE;

    int lane = threadIdx.x & 63;
    int wv   = threadIdx.x >> 6;
    int quad = lane >> 4;
    int r    = lane & 15;

    // stage: 1584 GLL units of 16B; LDS linear order == unit order
    for (int u = threadIdx.x; u < 1584; u += 256) {
        int fp  = u / 264;        // 66*4 units per fp row
        int rem = u - fp * 264;
        int tp  = rem >> 2;
        int q   = rem & 3;
        const u16* gp = Hb + ((size_t)(f0 + fp) * 514 + (t0 + tp)) * 32 + q * 8;
        GLL(gp, act + u * 8);
    }

    // B-fragments from park f32 weights (overlaps GLL)
    short8 bfrag[3][3][2];
    #pragma unroll
    for (int df = 0; df < 3; ++df)
        #pragma unroll
        for (int dt = 0; dt < 3; ++dt)
            #pragma unroll
            for (int ct = 0; ct < 2; ++ct) {
                short8 v;
                #pragma unroll
                for (int j = 0; j < 8; ++j) {
                    int co = ct * 16 + r, ci = quad * 8 + j;
                    v[j] = (short)f2bf(w[(co * 32 + ci) * 9 + df * 3 + dt]);
                }
                bfrag[df][dt][ct] = v;
            }
    __syncthreads();

    floatx4 acc[4][2];
    #pragma unroll
    for (int i = 0; i < 4; ++i)
        #pragma unroll
        for (int j = 0; j < 2; ++j)
            #pragma unroll
            for (int k = 0; k < 4; ++k) acc[i][j][k] = 0.f;

    int tw = wv * 16;
    #pragma unroll
    for (int fh = 0; fh < 6; ++fh) {
        short8 af[3];
        #pragma unroll
        for (int dt = 0; dt < 3; ++dt)
            af[dt] = *(const short8*)&act[((fh * 66) + tw + r + dt) * 32 + quad * 8];
        #pragma unroll
        for (int df = 0; df < 3; ++df) {
            int rel = fh - df;
            if (rel < 0 || rel >= 4) continue;
            #pragma unroll
            for (int dt = 0; dt < 3; ++dt)
                #pragma unroll
                for (int ct = 0; ct < 2; ++ct)
                    acc[rel][ct] = __builtin_amdgcn_mfma_f32_16x16x32_bf16(
                        af[dt], bfrag[df][dt][ct], acc[rel][ct], 0, 0, 0);
        }
    }

    // epilogue: row(m)=quad*4+reg -> t, col(n)=r -> co
    int tt = t0 + tw + quad * 4;
    #pragma unroll
    for (int rel = 0; rel < 4; ++rel)
        #pragma unroll
        for (int ct = 0; ct < 2; ++ct) {
            int f  = f0 + rel;
            int co = ct * 16 + r;
            size_t base = (((size_t)b * 32 + co) * 64 + f) * 512 + tt;
            float bs = bias[co];
            if (res) {
                float4 rv = *(const float4*)(res + base);
                float4 o;
                o.x = acc[rel][ct][0] + bs + rv.x;
                o.y = acc[rel][ct][1] + bs + rv.y;
                o.z = acc[rel][ct][2] + bs + rv.z;
                o.w = acc[rel][ct][3] + bs + rv.w;
                *(float4*)((float*)out + base) = o;
            } else {
                ushort4 o;
                o.x = f2bf(acc[rel][ct][0] + bs);
                o.y = f2bf(acc[rel][ct][1] + bs);
                o.z = f2bf(acc[rel][ct][2] + bs);
                o.w = f2bf(acc[rel][ct][3] + bs);
                *(ushort4*)((u16*)out + base) = o;
            }
        }
}

// ---------------- transpose X (b,c,f,t) f32 -> A[(t*16+b)][(c*64+f)] bf16 ----------------
__global__ __launch_bounds__(256) void transpose_k(const float* __restrict__ X, u16* __restrict__ A) {
    __shared__ float tile[64][65];
    int t0 = blockIdx.x * 64;
    int c  = blockIdx.y;
    int b  = blockIdx.z;
    const float* p = X + (((size_t)b * 32 + c) * 64) * 512 + t0;
    #pragma unroll
    for (int i = 0; i < 16; ++i) {
        int f = i * 4 + (threadIdx.x >> 6);
        int t = threadIdx.x & 63;
        tile[f][t] = p[(size_t)f * 512 + t];
    }
    __syncthreads();
    #pragma unroll
    for (int i = 0; i < 16; ++i) {
        int t = i * 4 + (threadIdx.x >> 6);
        int f = threadIdx.x & 63;
        A[((size_t)(t0 + t) * 16 + b) * 2048 + c * 64 + f] = f2bf(tile[f][t]);
    }
}

// ---------------- row layernorm, f32 in -> bf16 out ----------------
__global__ __launch_bounds__(256) void lnlast_k(const float* __restrict__ X, u16* __restrict__ Y,
                                                const float* __restrict__ g, const float* __restrict__ bt,
                                                int width) {
    int row = blockIdx.x;
    const float* p = X + (size_t)row * width;
    float s = 0.f, s2 = 0.f;
    for (int i = threadIdx.x; i < width; i += 256) { float v = p[i]; s += v; s2 += v * v; }
    #pragma unroll
    for (int off = 32; off; off >>= 1) { s += __shfl_down(s, off); s2 += __shfl_down(s2, off); }
    __shared__ float red[4][2];
    int wv = threadIdx.x >> 6;
    if ((threadIdx.x & 63) == 0) { red[wv][0] = s; red[wv][1] = s2; }
    __syncthreads();
    if (threadIdx.x == 0) {
        float a = 0.f, b2 = 0.f;
        for (int i = 0; i < 4; ++i) { a += red[i][0]; b2 += red[i][1]; }
        float m = a / width;
        float var = fmaxf(b2 / width - m * m, 0.f);
        red[0][0] = m; red[0][1] = rsqrtf(var + 1e-5f);
    }
    __syncthreads();
    float m = red[0][0], rs = red[0][1];
    u16* q = Y + (size_t)row * width;
    for (int i = threadIdx.x; i < width; i += 256)
        q[i] = f2bf((p[i] - m) * rs * g[i] + bt[i]);
}

// ---------------- m97-style MFMA GEMM: C = A @ Bt^T, 128x128, BK=32, GLL staging ----------
// obf: 1 -> bf16 output, 0 -> f32. bn >= nsplit uses (A2, C2) with col -= nsplit.
__global__ __launch_bounds__(256) void gemm_bt(const u16* __restrict__ A, const u16* __restrict__ A2,
                                               int lda, const u16* __restrict__ Bt, int ldb,
                                               void* __restrict__ C, void* __restrict__ C2,
                                               int ldc, int nsplit,
                                               const float* __restrict__ bias, int relu, int K,
                                               int obf) {
    __shared__ u16 As[128 * 32];
    __shared__ u16 Bs[128 * 32];
    int tid  = threadIdx.x;
    int bm   = blockIdx.x * 128;
    int bn   = blockIdx.y * 128;
    const u16* Ab = A;
    void* Cb = C;
    int cn = bn;
    if (bn >= nsplit) { Ab = A2; Cb = C2; cn = bn - nsplit; }

    int lane = tid & 63;
    int wv   = tid >> 6;
    int quad = lane >> 4;
    int r    = lane & 15;
    int wm   = (wv >> 1) * 64;
    int wn   = (wv & 1) * 64;

    floatx4 acc[4][4];
    #pragma unroll
    for (int i = 0; i < 4; ++i)
        #pragma unroll
        for (int j = 0; j < 4; ++j)
            #pragma unroll
            for (int k = 0; k < 4; ++k) acc[i][j][k] = 0.f;

    int row0 = tid >> 2;
    int ks0  = (tid & 3) * 8;
    const u16* Abase  = Ab + (size_t)(bm + row0) * lda + ks0;
    const u16* Abase2 = Ab + (size_t)(bm + 64 + row0) * lda + ks0;
    const u16* Bbase  = Bt + (size_t)(bn + row0) * ldb + ks0;
    const u16* Bbase2 = Bt + (size_t)(bn + 64 + row0) * ldb + ks0;
    u16* AsD  = As + tid * 8;
    u16* AsD2 = As + 2048 + tid * 8;
    u16* BsD  = Bs + tid * 8;
    u16* BsD2 = Bs + 2048 + tid * 8;

    for (int k0 = 0; k0 < K; k0 += 32) {
        GLL(Abase + k0, AsD);
        GLL(Abase2 + k0, AsD2);
        GLL(Bbase + k0, BsD);
        GLL(Bbase2 + k0, BsD2);
        __syncthreads();
        short8 af[4], bf[4];
        #pragma unroll
        for (int mi = 0; mi < 4; ++mi) af[mi] = *(const short8*)&As[(wm + mi * 16 + r) * 32 + quad * 8];
        #pragma unroll
        for (int ni = 0; ni < 4; ++ni) bf[ni] = *(const short8*)&Bs[(wn + ni * 16 + r) * 32 + quad * 8];
        #pragma unroll
        for (int mi = 0; mi < 4; ++mi)
            #pragma unroll
            for (int ni = 0; ni < 4; ++ni)
                acc[mi][ni] = __builtin_amdgcn_mfma_f32_16x16x32_bf16(af[mi], bf[ni], acc[mi][ni], 0, 0, 0);
        __syncthreads();
    }

    #pragma unroll
    for (int mi = 0; mi < 4; ++mi)
        #pragma unroll
        for (int ni = 0; ni < 4; ++ni) {
            int col = cn + wn + ni * 16 + r;
            float bs = bias ? bias[col] : 0.f;
            #pragma unroll
            for (int reg = 0; reg < 4; ++reg) {
                int row = bm + wm + mi * 16 + quad * 4 + reg;
                float v = acc[mi][ni][reg] + bs;
                if (relu) v = fmaxf(v, 0.f);
                if (obf) ((u16*)Cb)[(size_t)row * ldc + col] = f2bf(v);
                else     ((float*)Cb)[(size_t)row * ldc + col] = v;
            }
        }
}

// ---------------- SRU recurrence, TC-step chunk, both dirs, bf16 U, prefetch ----------------
#define TC 256
__global__ __launch_bounds__(64) void scan_k(const u16* __restrict__ Uf, const u16* __restrict__ Ub,
                                             const float* __restrict__ Xp, float* __restrict__ Xn,
                                             float* __restrict__ cstate, const float* __restrict__ vv,
                                             const float* __restrict__ bb, int t0f, int t0b, int init) {
    int gid = blockIdx.x * 64 + threadIdx.x;  // 16384
    int d  = gid >> 13;
    int b  = (gid >> 9) & 15;
    int h  = gid & 511;
    float v0 = vv[(d * 2 + 0) * 512 + h];
    float v1 = vv[(d * 2 + 1) * 512 + h];
    float b0 = bb[(d * 2 + 0) * 512 + h];
    float b1 = bb[(d * 2 + 1) * 512 + h];
    const u16* u = (d ? Ub : Uf) + (size_t)b * 1536 + h;
    int t0 = d ? t0b : t0f;
    const float* xb = Xp + (size_t)b * 1024 + d * 512 + h;
    float*       ob = Xn + (size_t)b * 1024 + d * 512 + h;
    float c = init ? 0.f : cstate[gid];
    int sl = d ? (TC - 1) : 0;
    int stp = d ? -1 : 1;
    size_t ro = (size_t)sl * 16 * 1536;
    size_t xo = (size_t)(t0 + sl) * 16 * 1024;
    float u0 = bf2f(u[ro]), fp_ = bf2f(u[ro + 512]), rp_ = bf2f(u[ro + 1024]);
    float xr = xb[xo];
    for (int s = 0; s < TC; ++s) {
        int nsl = sl + stp;
        size_t nro = (size_t)nsl * 16 * 1536;
        size_t nxo = (size_t)(t0 + nsl) * 16 * 1024;
        float nu0 = 0.f, nfp = 0.f, nrp = 0.f, nxr = 0.f;
        if (s + 1 < TC) {  // prefetch next step, independent of c-chain
            nu0 = bf2f(u[nro]); nfp = bf2f(u[nro + 512]); nrp = bf2f(u[nro + 1024]);
            nxr = xb[nxo];
        }
        float f = 1.f / (1.f + __expf(-(fp_ + b0 + v0 * c)));
        float r = 1.f / (1.f + __expf(-(rp_ + b1 + v1 * c)));
        c = f * c + (1.f - f) * u0;
        float th = 1.f - 2.f / (__expf(2.f * c) + 1.f);
        ob[xo] = r * th + (1.f - r) * xr;
        u0 = nu0; fp_ = nfp; rp_ = nrp; xr = nxr; sl = nsl; ro = nro; xo = nxo;
    }
    cstate[gid] = c;
}

// ---------------- classifier head ----------------
__global__ __launch_bounds__(256) void cls2_k(const float* __restrict__ FC1, const float* __restrict__ W2,
                                              const float* __restrict__ b2, void* __restrict__ out,
                                              const int* __restrict__ flag) {
    int isf32 = *flag;
    int row = blockIdx.x * 4 + (threadIdx.x >> 6);
    int v   = threadIdx.x & 63;
    if (v >= 29) return;
    const float* p = FC1 + (size_t)row * 512;
    float acc = 0.f;
    for (int k = 0; k < 512; ++k) acc = fmaf(p[k], W2[k * 29 + v], acc);
    acc += b2[v];
    int t = row >> 4, b = row & 15;
    size_t oi = ((size_t)b * 512 + t) * 29 + v;
    if (isf32) ((float*)out)[oi] = acc;
    else       ((u16*)out)[oi]   = f2bf(acc);
}

// ---------------- launch ----------------
extern "C" void kernel_launch(void* const* d_in, const int* in_sizes, int n_in,
                              void* d_out, int out_size, void* d_ws, size_t ws_size,
                              hipStream_t stream) {
    const void* x      = d_in[0];
    const void* proj_w = d_in[11];
    const void* sru_w  = d_in[12];
    const void* cls_w1 = d_in[19];

    float* ws = (float*)d_ws;
    // float offsets
    const size_t O_X    = 0;          // X f32 NCHW residual [0, 16.78M)
    const size_t O_C    = 16777216;   // C bf16 NCHW conv1-out [16.78M, 25.17M)
    const size_t O_HA   = 25165824;   // Ha bf16 halo NHWC (8684544 floats)
    const size_t O_SM   = 33850368;   // 262144
    const size_t O_SR   = 34112512;   // 262144
    const size_t O_CST  = 34374656;   // 16384
    const size_t O_PARK = 34391040;   // 92448
    const size_t O_FLAG = 34483488;   // 16
    const size_t TOTAL  = 34483504;   // 131.55 MiB
    if (ws_size < TOTAL * sizeof(float)) {
        fill_k<<<(out_size + 255) / 256, 256, 0, stream>>>((float*)d_out, out_size);
        return;  // diagnostic: absmax ~1e6 => ws too small
    }

    float* X   = ws + O_X;
    u16*   C   = (u16*)(ws + O_C);
    u16*   HA  = (u16*)(ws + O_HA);
    float* SM  = ws + O_SM;
    float* SR  = ws + O_SR;
    float* CST = ws + O_CST;
    float* PK  = ws + O_PARK;
    int*   FLG = (int*)(ws + O_FLAG);

    // lifetime-aliased regions:
    u16*   Abf = (u16*)(ws + O_C);       // [16.78M, 25.17M) GEMM-A (C dead after conv)
    u16*   BtP = (u16*)(ws + 0);         // [0, 1.05M) proj B^T (X dead after transpose)
    float* XP0 = ws + 25165824;          // [25.17M, 33.55M) RNN ping (Ha dead)
    u16*   XL  = (u16*)(ws + 0);         // [0, 4.19M) LN out bf16
    float* XP1 = ws + 4194304;           // [4.19M, 12.58M) RNN pong
    u16*   Uf  = (u16*)(ws + 12582912);  // [12.58M, 15.73M) u fwd bf16 4096x1536
    u16*   Ub  = (u16*)(ws + 15728640);  // [15.73M, 18.87M) u bwd bf16
    u16*   BtS = (u16*)(ws + 18874368);  // [18.87M, 23.59M) sru B^T, 3 x 3072x1024
    u16*   BtC = (u16*)(ws + O_SM);      // cls_w1 B^T (stats dead)
    float* FC1 = ws + 12582912;          // [12.58M, 16.78M) classifier (U dead)

    float* p_cnn_w = PK + 0;      float* p_cnn_b = PK + 288;
    float* p_rw1   = PK + 320;    float* p_rb1   = PK + 27968;
    float* p_rw2   = PK + 28064;  float* p_rb2   = PK + 55712;
    float* p_l1g   = PK + 55808;  float* p_l1b   = PK + 56000;
    float* p_l2g   = PK + 56192;  float* p_l2b   = PK + 56384;
    float* p_sv    = PK + 56576;  float* p_sb    = PK + 62720;
    float* p_slng  = PK + 68864;  float* p_slnb  = PK + 71936;
    float* p_clng  = PK + 75008;  float* p_clnb  = PK + 76032;
    float* p_cb1   = PK + 77056;  float* p_cw2   = PK + 77568;
    float* p_cb2   = PK + 92416;

    sniff_k<<<1, 256, 0, stream>>>((const u16*)x, FLG);

    CvtArgs ca;
    const int srcidx[19] = {1,2,3,4,5,6,7,8,9,10,13,14,15,16,17,18,20,21,22};
    const int lens[19]   = {288,32,27648,96,27648,96,192,192,192,192,6144,6144,3072,3072,1024,1024,512,14848,29};
    const int offs[19]   = {0,288,320,27968,28064,55712,55808,56000,56192,56384,56576,62720,68864,71936,75008,76032,77056,77568,92416};
    for (int i = 0; i < 19; ++i) { ca.src[i] = d_in[srcidx[i]]; ca.len[i] = lens[i]; ca.off[i] = offs[i]; }
    cvtall_k<<<dim3(108, 19), 256, 0, stream>>>(ca, PK, FLG);

    zero_k<<<2048, 256, 0, stream>>>((float4*)HA, 2171136);  // zero halo tensor once
    conv1_k<<<65536, 256, 0, stream>>>(x, p_cnn_w, p_cnn_b, X, FLG);

    for (int i = 0; i < 3; ++i) {
        stats_k<<<1024, 256, 0, stream>>>(X, 0, SM, SR);
        apply_k<<<dim3(64, 16), 256, 0, stream>>>(X, 0, SM, SR, p_l1g + i * 64, p_l1b + i * 64, HA);
        convm_k<<<dim3(16, 8, 16), 256, 0, stream>>>(HA, C, p_rw1 + i * 9216, p_rb1 + i * 32, nullptr);
        stats_k<<<1024, 256, 0, stream>>>(C, 1, SM, SR);
        apply_k<<<dim3(64, 16), 256, 0, stream>>>(C, 1, SM, SR, p_l2g + i * 64, p_l2b + i * 64, HA);
        convm_k<<<dim3(16, 8, 16), 256, 0, stream>>>(HA, X, p_rw2 + i * 9216, p_rb2 + i * 32, X);
    }

    transpose_k<<<dim3(8, 32, 16), 256, 0, stream>>>(X, Abf);
    wtr_k<<<dim3(32, 16), 256, 0, stream>>>(proj_w, 1024, 0, BtP, 2048, FLG);
    gemm_bt<<<dim3(64, 8), 256, 0, stream>>>(Abf, Abf, 2048, BtP, 2048, XP0, XP0, 1024,
                                             1 << 30, nullptr, 0, 2048, 0);

    for (int l = 0; l < 3; ++l)
        wtr_k<<<dim3(16, 48), 256, 0, stream>>>(sru_w, 3072, (size_t)l * 3145728,
                                                BtS + (size_t)l * 3145728, 1024, FLG);
    wtr_k<<<dim3(16, 8), 256, 0, stream>>>(cls_w1, 512, 0, BtC, 1024, FLG);

    float* cur = XP0;
    float* nxt = XP1;
    for (int l = 0; l < 3; ++l) {
        lnlast_k<<<8192, 256, 0, stream>>>(cur, XL, p_slng + l * 1024, p_slnb + l * 1024, 1024);
        const u16* Btl = BtS + (size_t)l * 3145728;
        for (int j = 0; j < 2; ++j) {
            int t0f = j * TC;
            int t0b = (1 - j) * TC;
            // fused fwd+bwd u-GEMM, bf16 out: cols [0,1536) fwd rows t0f.., cols [1536,3072) bwd rows t0b..
            gemm_bt<<<dim3(32, 24), 256, 0, stream>>>(XL + (size_t)t0f * 16 * 1024,
                                                      XL + (size_t)t0b * 16 * 1024, 1024,
                                                      Btl, 1024, Uf, Ub, 1536, 1536,
                                                      nullptr, 0, 1024, 1);
            scan_k<<<256, 64, 0, stream>>>(Uf, Ub, cur, nxt, CST,
                                           p_sv + l * 2048, p_sb + l * 2048, t0f, t0b, j == 0);
        }
        float* tmp = cur; cur = nxt; nxt = tmp;
    }

    lnlast_k<<<8192, 256, 0, stream>>>(cur, XL, p_clng, p_clnb, 1024);
    gemm_bt<<<dim3(64, 4), 256, 0, stream>>>(XL, XL, 1024, BtC, 1024, FC1, FC1, 512,
                                             1 << 30, p_cb1, 1, 1024, 0);
    cls2_k<<<2048, 256, 0, stream>>>(FC1, p_cw2, p_cb2, d_out, FLG);
}